// Round 6
// baseline (2204.172 us; speedup 1.0000x reference)
//
#include <hip/hip_runtime.h>
#include <math.h>

#define NN 50000
#define EE 400000
#define LEE 1600000
#define BBATCH 256
#define FF 64
#define EDD 16
#define NITER 3
#define SFD 384

#define CDIV(a,b) (((a)+(b)-1)/(b))

typedef unsigned short ushort_t;
typedef __attribute__((ext_vector_type(8))) short bf16x8;
typedef __attribute__((ext_vector_type(4))) float f32x4;

// ---------- helpers ----------
__device__ inline float b2f(ushort_t u) { return __uint_as_float(((unsigned)u) << 16); }
__device__ inline ushort_t f2b(float f) {   // RNE
    unsigned u = __float_as_uint(f);
    return (ushort_t)((u + 0x7fffu + ((u >> 16) & 1u)) >> 16);
}

// ---------- small CSR-build kernels ----------
__global__ void k_hist(const int* __restrict__ idx, int n, int* __restrict__ cnt) {
    int i = blockIdx.x * blockDim.x + threadIdx.x;
    if (i < n) atomicAdd(&cnt[idx[i]], 1);
}
__global__ void k_part(const int* __restrict__ in, int n, int* __restrict__ part) {
    __shared__ int s[256];
    int i = blockIdx.x * 256 + threadIdx.x;
    s[threadIdx.x] = (i < n) ? in[i] : 0;
    __syncthreads();
    for (int off = 128; off > 0; off >>= 1) {
        if (threadIdx.x < off) s[threadIdx.x] += s[threadIdx.x + off];
        __syncthreads();
    }
    if (threadIdx.x == 0) part[blockIdx.x] = s[0];
}
__global__ void k_scan_single(int* __restrict__ a, int n) {
    __shared__ int s[256];
    int v = (threadIdx.x < n) ? a[threadIdx.x] : 0;
    s[threadIdx.x] = v; __syncthreads();
    for (int off = 1; off < 256; off <<= 1) {
        int t = (threadIdx.x >= off) ? s[threadIdx.x - off] : 0;
        __syncthreads(); s[threadIdx.x] += t; __syncthreads();
    }
    if (threadIdx.x < n) a[threadIdx.x] = s[threadIdx.x] - v;
}
__global__ void k_scan_add(int* __restrict__ a, int n, const int* __restrict__ off) {
    __shared__ int s[256];
    int i = blockIdx.x * 256 + threadIdx.x;
    int v = (i < n) ? a[i] : 0;
    s[threadIdx.x] = v; __syncthreads();
    for (int o = 1; o < 256; o <<= 1) {
        int t = (threadIdx.x >= o) ? s[threadIdx.x - o] : 0;
        __syncthreads(); s[threadIdx.x] += t; __syncthreads();
    }
    if (i < n) a[i] = s[threadIdx.x] - v + off[blockIdx.x];
}
__global__ void k_scan_out(const int* __restrict__ in, int n, const int* __restrict__ boff,
                           int* __restrict__ out) {
    __shared__ int s[256];
    int i = blockIdx.x * 256 + threadIdx.x;
    int v = (i < n) ? in[i] : 0;
    s[threadIdx.x] = v; __syncthreads();
    for (int o = 1; o < 256; o <<= 1) {
        int t = (threadIdx.x >= o) ? s[threadIdx.x - o] : 0;
        __syncthreads(); s[threadIdx.x] += t; __syncthreads();
    }
    if (i < n) out[i] = s[threadIdx.x] - v + boff[blockIdx.x];
    if (i == n - 1) out[n] = s[threadIdx.x] + boff[blockIdx.x];
}
__global__ void k_fill_lg(const int* __restrict__ lg, const int* __restrict__ rowptr,
                          int* __restrict__ cnt, int* __restrict__ srcidx) {
    int i = blockIdx.x * blockDim.x + threadIdx.x;
    if (i >= LEE) return;
    int d = lg[LEE + i];
    int pos = rowptr[d] + atomicAdd(&cnt[d], 1);
    srcidx[pos] = lg[i];
}
__global__ void k_fill_n(const int* __restrict__ ei, const int* __restrict__ rowptr,
                         int* __restrict__ cnt, int* __restrict__ nidx) {
    int i = blockIdx.x * blockDim.x + threadIdx.x;
    if (i >= EE) return;
    int d = ei[EE + i];
    int pos = rowptr[d] + atomicAdd(&cnt[d], 1);
    nidx[pos] = i;
}

// ---------- main kernels ----------

// xu = bf16(x @ W_u), xv = bf16(x @ W_v)
__global__ void k_node_mm(const float* __restrict__ x, const float* __restrict__ Wu,
                          const float* __restrict__ Wv, ushort_t* __restrict__ xu,
                          ushort_t* __restrict__ xv) {
    __shared__ float su[64 * 64];
    __shared__ float sv[64 * 64];
    int tid = threadIdx.x;
    for (int i = tid; i < 64 * 64; i += blockDim.x) { su[i] = Wu[i]; sv[i] = Wv[i]; }
    __syncthreads();
    int row = blockIdx.x * 4 + (tid >> 6);
    int f = tid & 63;
    if (row >= NN) return;
    const float* xr = x + (long long)row * 64;
    float au = 0.f, av = 0.f;
    #pragma unroll
    for (int k = 0; k < 64; ++k) {
        float xv_ = xr[k];
        au += xv_ * su[k * 64 + f];
        av += xv_ * sv[k * 64 + f];
    }
    xu[(long long)row * 64 + f] = f2b(au);
    xv[(long long)row * 64 + f] = f2b(av);
}

// eab[e][f] = bf16((xu[ei0] + xv[ei1] + eattr @ W_e)/3); 2 feats/lane, 2 edges/wave
__global__ void k_ea_b16(const ushort_t* __restrict__ xu, const ushort_t* __restrict__ xv,
                         const float* __restrict__ eattr, const float* __restrict__ We,
                         const int* __restrict__ ei, ushort_t* __restrict__ eab) {
    __shared__ float swe[16 * 64];
    int tid = threadIdx.x;
    for (int i = tid; i < 1024; i += 256) swe[i] = We[i];
    __syncthreads();
    int e = blockIdx.x * 8 + (tid >> 5);
    int f2 = (tid & 31) * 2;
    if (e >= EE) return;
    int s = ei[e];
    int d = ei[EE + e];
    unsigned us = *(const unsigned*)&xu[(long long)s * 64 + f2];
    unsigned ud = *(const unsigned*)&xv[(long long)d * 64 + f2];
    const float* ar = eattr + (long long)e * 16;
    float a0 = 0.f, a1 = 0.f;
    #pragma unroll
    for (int k = 0; k < 16; ++k) {
        float w = ar[k];
        a0 += w * swe[k * 64 + f2];
        a1 += w * swe[k * 64 + f2 + 1];
    }
    float v0 = (b2f((ushort_t)us) + b2f((ushort_t)ud) + a0) * (1.0f / 3.0f);
    float v1 = (b2f((ushort_t)(us >> 16)) + b2f((ushort_t)(ud >> 16)) + a1) * (1.0f / 3.0f);
    *(unsigned*)&eab[(long long)e * 64 + f2] = (unsigned)f2b(v0) | ((unsigned)f2b(v1) << 16);
}

// out[d] = eab[d] + sum_{src} prev[src]; xw[d] = out[d].gatW. 2 feats/lane, 2 edges/wave
__global__ void k_mp_gather(const ushort_t* __restrict__ prev,
                            const ushort_t* __restrict__ eab,
                            const int* __restrict__ rowptr, const int* __restrict__ srcidx,
                            const float* __restrict__ gatW,
                            ushort_t* __restrict__ outb, float* __restrict__ xw) {
    int tid = threadIdx.x;
    int d = blockIdx.x * 8 + (tid >> 5);
    int f2 = (tid & 31) * 2;
    if (d >= EE) return;
    unsigned ue = *(const unsigned*)&eab[(long long)d * 64 + f2];
    float a0 = b2f((ushort_t)ue), a1 = b2f((ushort_t)(ue >> 16));
    int p0 = rowptr[d], p1 = rowptr[d + 1];
    int j = p0;
    for (; j + 4 <= p1; j += 4) {
        int s0 = srcidx[j], s1 = srcidx[j + 1], s2 = srcidx[j + 2], s3 = srcidx[j + 3];
        unsigned u0 = *(const unsigned*)&prev[(long long)s0 * 64 + f2];
        unsigned u1 = *(const unsigned*)&prev[(long long)s1 * 64 + f2];
        unsigned u2 = *(const unsigned*)&prev[(long long)s2 * 64 + f2];
        unsigned u3 = *(const unsigned*)&prev[(long long)s3 * 64 + f2];
        a0 += (b2f((ushort_t)u0) + b2f((ushort_t)u1)) + (b2f((ushort_t)u2) + b2f((ushort_t)u3));
        a1 += (b2f((ushort_t)(u0 >> 16)) + b2f((ushort_t)(u1 >> 16))) +
              (b2f((ushort_t)(u2 >> 16)) + b2f((ushort_t)(u3 >> 16)));
    }
    for (; j < p1; ++j) {
        unsigned u0 = *(const unsigned*)&prev[(long long)srcidx[j] * 64 + f2];
        a0 += b2f((ushort_t)u0);
        a1 += b2f((ushort_t)(u0 >> 16));
    }
    *(unsigned*)&outb[(long long)d * 64 + f2] = (unsigned)f2b(a0) | ((unsigned)f2b(a1) << 16);
    float w = a0 * gatW[f2] + a1 * gatW[f2 + 1];
    #pragma unroll
    for (int o = 16; o > 0; o >>= 1) w += __shfl_down(w, o, 32);
    if ((tid & 31) == 0) xw[d] = w;
}

// fused GAT: per dst edge, serial max / exp-sum / weighted-sum over CSR in-edges + self-loop
__global__ void k_gat_fused(const float* __restrict__ xw,
                            const int* __restrict__ rowptr, const int* __restrict__ srcidx,
                            const float* __restrict__ att_s, const float* __restrict__ att_d,
                            const float* __restrict__ gbias, float* __restrict__ xc) {
    int e = blockIdx.x * blockDim.x + threadIdx.x;
    if (e >= EE) return;
    float as = att_s[0], ad = att_d[0];
    float xwd = xw[e];
    float adt = xwd * ad;
    float aself = xwd * as + adt;
    if (aself < 0.f) aself *= 0.2f;
    int p0 = rowptr[e], p1 = rowptr[e + 1];
    float m = aself;
    for (int j = p0; j < p1; ++j) {
        float a = xw[srcidx[j]] * as + adt;
        if (a < 0.f) a *= 0.2f;
        m = fmaxf(m, a);
    }
    float ssum = expf(aself - m);
    float wsum = ssum * xwd;
    for (int j = p0; j < p1; ++j) {
        float xs = xw[srcidx[j]];
        float a = xs * as + adt;
        if (a < 0.f) a *= 0.2f;
        float ev = expf(a - m);
        ssum += ev;
        wsum += ev * xs;
    }
    xc[e] = wsum / (ssum + 1e-16f) + gbias[0];
}

__global__ void k_batchptr(const int* __restrict__ batch, int* __restrict__ bptr) {
    int e = blockIdx.x * blockDim.x + threadIdx.x;
    if (e >= EE) return;
    int b = batch[e];
    int bp = (e == 0) ? -1 : batch[e - 1];
    for (int q = bp + 1; q <= b; ++q) bptr[q] = e;
    if (e == EE - 1)
        for (int q = b + 1; q <= BBATCH; ++q) bptr[q] = EE;
}

// per-batch: softmax(xc) over segment, weighted-sum pool of bf16 out
__global__ void k_pool(const float* __restrict__ xc, const ushort_t* __restrict__ out,
                       const int* __restrict__ bptr, float* __restrict__ gout) {
    int b = blockIdx.x;
    int p0 = bptr[b], p1 = bptr[b + 1];
    __shared__ float red[256];
    int tid = threadIdx.x;
    float mx = -INFINITY;
    for (int e = p0 + tid; e < p1; e += 256) mx = fmaxf(mx, xc[e]);
    red[tid] = mx; __syncthreads();
    for (int s = 128; s > 0; s >>= 1) { if (tid < s) red[tid] = fmaxf(red[tid], red[tid + s]); __syncthreads(); }
    float m = red[0]; __syncthreads();
    float sm = 0.f;
    for (int e = p0 + tid; e < p1; e += 256) sm += expf(xc[e] - m);
    red[tid] = sm; __syncthreads();
    for (int s = 128; s > 0; s >>= 1) { if (tid < s) red[tid] += red[tid + s]; __syncthreads(); }
    float ssum = red[0] + 1e-16f; __syncthreads();
    int f = tid & 63, chunk = tid >> 6;
    float acc = 0.f;
    for (int e = p0 + chunk; e < p1; e += 4) {
        float w = expf(xc[e] - m);
        acc += w * b2f(out[(long long)e * 64 + f]);
    }
    red[tid] = acc; __syncthreads();
    if (chunk == 0) {
        float tot = red[f] + red[64 + f] + red[128 + f] + red[192 + f];
        gout[b * 64 + f] = tot / ssum;
    }
}

__global__ void k_gout_mm(const float* __restrict__ gout, const float* __restrict__ Wg,
                          const float* __restrict__ bg, float* __restrict__ gt) {
    __shared__ float sw[64 * 64];
    int tid = threadIdx.x;
    for (int i = tid; i < 4096; i += blockDim.x) sw[i] = Wg[i];
    __syncthreads();
    int row = blockIdx.x * 4 + (tid >> 6);
    int f = tid & 63;
    if (row >= BBATCH) return;
    const float* gr = gout + row * 64;
    float acc = bg[f];
    #pragma unroll
    for (int k = 0; k < 64; ++k) acc += gr[k] * sw[k * 64 + f];
    gt[row * 64 + f] = tanhf(acc);
}

__global__ void k_att(const float* __restrict__ g0, const float* __restrict__ g1,
                      const float* __restrict__ g2, const float* __restrict__ a,
                      const float* __restrict__ abias, float* __restrict__ sc) {
    int b = blockIdx.x;
    int f = threadIdx.x; // 64 threads
    float v0 = g0[b * 64 + f] * a[f * 3 + 0];
    float v1 = g1[b * 64 + f] * a[f * 3 + 1];
    float v2 = g2[b * 64 + f] * a[f * 3 + 2];
    #pragma unroll
    for (int o = 32; o > 0; o >>= 1) {
        v0 += __shfl_down(v0, o, 64);
        v1 += __shfl_down(v1, o, 64);
        v2 += __shfl_down(v2, o, 64);
    }
    if (f == 0) {
        float s0 = v0 + abias[0], s1 = v1 + abias[1], s2 = v2 + abias[2];
        float m = fmaxf(s0, fmaxf(s1, s2));
        float e0 = expf(s0 - m), e1 = expf(s1 - m), e2 = expf(s2 - m);
        float inv = 1.0f / (e0 + e1 + e2);
        sc[b * 3 + 0] = e0 * inv; sc[b * 3 + 1] = e1 * inv; sc[b * 3 + 2] = e2 * inv;
    }
}

// o1 <- sum_t o_t * sc_t[batch]   (elementwise, in place on o1)
__global__ void k_comb(ushort_t* __restrict__ o1, const ushort_t* __restrict__ o2,
                       const ushort_t* __restrict__ o3, const float* __restrict__ sc,
                       const int* __restrict__ batch) {
    long long idx = (long long)blockIdx.x * blockDim.x + threadIdx.x;
    if (idx >= (long long)EE * 64) return;
    int e = (int)(idx >> 6);
    int b = batch[e];
    float v = b2f(o1[idx]) * sc[b * 3] + b2f(o2[idx]) * sc[b * 3 + 1] + b2f(o3[idx]) * sc[b * 3 + 2];
    o1[idx] = f2b(v);
}

// xnb[n] = bf16(x[n] + sum over in-edges of comb[e])
__global__ void k_node_gather(const ushort_t* __restrict__ comb, const int* __restrict__ nrow,
                              const int* __restrict__ nidx, const float* __restrict__ x,
                              ushort_t* __restrict__ xnb) {
    int tid = threadIdx.x;
    int n = blockIdx.x * 4 + (tid >> 6);
    int f = tid & 63;
    if (n >= NN) return;
    float acc = x[(long long)n * 64 + f];
    int p0 = nrow[n], p1 = nrow[n + 1];
    int j = p0;
    for (; j + 4 <= p1; j += 4) {
        int e0 = nidx[j], e1 = nidx[j + 1], e2 = nidx[j + 2], e3 = nidx[j + 3];
        float v0 = b2f(comb[(long long)e0 * 64 + f]);
        float v1 = b2f(comb[(long long)e1 * 64 + f]);
        float v2 = b2f(comb[(long long)e2 * 64 + f]);
        float v3 = b2f(comb[(long long)e3 * 64 + f]);
        acc += (v0 + v1) + (v2 + v3);
    }
    for (; j < p1; ++j) acc += b2f(comb[(long long)nidx[j] * 64 + f]);
    xnb[(long long)n * 64 + f] = f2b(acc);
}

// column stats of a bf16 matrix (blockDim.x == ncols)
__global__ void k_colstats_b16(const ushort_t* __restrict__ X, int ncols, int nrows,
                               float* __restrict__ csum, float* __restrict__ csumsq) {
    int c = threadIdx.x;
    int rpb = CDIV(nrows, (int)gridDim.x);
    int r0 = blockIdx.x * rpb;
    int r1 = min(r0 + rpb, nrows);
    float s = 0.f, s2 = 0.f;
    for (int r = r0; r < r1; ++r) {
        float v = b2f(X[(long long)r * ncols + c]);
        s += v; s2 += v * v;
    }
    atomicAdd(&csum[c], s);
    atomicAdd(&csumsq[c], s2);
}

// Full-width LinBlock GEMM: C = scale*(act(bn(A)) @ W + bias + res)
// A bf16 [nrows,K]; W f32 [K,MT]; tile 64 rows x MT cols (A read once).
// BN scale/offset derived in prologue from raw column sums. Output stats fused
// (wave-reduced atomics). Cb bf16 and/or Cf f32 outputs.
template<int MT>
__global__ __launch_bounds__(512) void k_gemm_lb(
    const ushort_t* __restrict__ A, const float* __restrict__ W,
    const float* __restrict__ bias, const ushort_t* __restrict__ resb,
    const float* __restrict__ csum, const float* __restrict__ csumsq,
    const float* __restrict__ g, const float* __restrict__ bb,
    const float* __restrict__ pr, float scale, int nrows, int K,
    ushort_t* __restrict__ Cb, float* __restrict__ Cf,
    float* __restrict__ osum, float* __restrict__ osumsq) {
    constexpr int NF = MT / 32;   // frags per wave along M (2 col-groups)
    __shared__ ushort_t sA[64][40];
    __shared__ ushort_t sB[MT][40];
    __shared__ float sScl[SFD], sOff[SFD];
    int tid = threadIdx.x;
    int wave = tid >> 6, lane = tid & 63;
    int l16 = lane & 15, klo = lane >> 4;
    int rowg = wave >> 1, colg = wave & 1;
    long long rowBase = (long long)blockIdx.x * 64;
    float prs = pr ? pr[0] : 1.0f;
    const float invn = 1.0f / (float)NN;
    for (int c = tid; c < K; c += 512) {
        float mean = csum[c] * invn;
        float var = csumsq[c] * invn - mean * mean;
        float scl = rsqrtf(var + 1e-5f) * g[c];
        sScl[c] = scl;
        sOff[c] = bb[c] - mean * scl;
    }
    __syncthreads();
    f32x4 acc[NF] = {};
    for (int k0 = 0; k0 < K; k0 += 32) {
        // stage A: 64 rows x 32 k, BN+act fused, bf16 (one uint2 per thread)
        {
            int i4 = tid * 4;
            int r = i4 >> 5, kk = i4 & 31;
            long long gr = rowBase + r;
            unsigned lo = 0, hi = 0;
            if (gr < nrows) {
                const ushort_t* ap = &A[gr * K + k0 + kk];
                unsigned raw0 = *(const unsigned*)ap;
                unsigned raw1 = *(const unsigned*)(ap + 2);
                float t0 = b2f((ushort_t)raw0) * sScl[k0 + kk] + sOff[k0 + kk];
                float t1 = b2f((ushort_t)(raw0 >> 16)) * sScl[k0 + kk + 1] + sOff[k0 + kk + 1];
                float t2 = b2f((ushort_t)raw1) * sScl[k0 + kk + 2] + sOff[k0 + kk + 2];
                float t3 = b2f((ushort_t)(raw1 >> 16)) * sScl[k0 + kk + 3] + sOff[k0 + kk + 3];
                if (t0 < 0.f) t0 *= prs;
                if (t1 < 0.f) t1 *= prs;
                if (t2 < 0.f) t2 *= prs;
                if (t3 < 0.f) t3 *= prs;
                lo = (unsigned)f2b(t0) | ((unsigned)f2b(t1) << 16);
                hi = (unsigned)f2b(t2) | ((unsigned)f2b(t3) << 16);
            }
            uint2 pk; pk.x = lo; pk.y = hi;
            *(uint2*)&sA[r][kk] = pk;
        }
        // stage B: 32 k-rows x MT cols of W -> bf16 transposed [col][k]
        for (int i = tid; i < 32 * MT; i += 512) {
            int col = i % MT, kk = i / MT;
            sB[col][kk] = f2b(W[(long long)(k0 + kk) * MT + col]);
        }
        __syncthreads();
        bf16x8 af = *(const bf16x8*)&sA[rowg * 16 + l16][klo * 8];
        #pragma unroll
        for (int n = 0; n < NF; ++n) {
            bf16x8 bf = *(const bf16x8*)&sB[colg * (MT / 2) + n * 16 + l16][klo * 8];
            acc[n] = __builtin_amdgcn_mfma_f32_16x16x32_bf16(af, bf, acc[n], 0, 0, 0);
        }
        __syncthreads();
    }
    // epilogue: C/D col=lane&15, row=(lane>>4)*4+reg; fused bias/res/scale/stats
    #pragma unroll
    for (int n = 0; n < NF; ++n) {
        int col = colg * (MT / 2) + n * 16 + l16;
        long long row0 = rowBase + rowg * 16 + klo * 4;
        float bcol = bias[col];
        float s = 0.f, s2 = 0.f;
        #pragma unroll
        for (int r = 0; r < 4; ++r) {
            long long row = row0 + r;
            if (row < nrows) {
                float v = acc[n][r] + bcol;
                if (resb) v += b2f(resb[row * MT + col]);
                v *= scale;
                if (Cf) Cf[row * MT + col] = v;
                if (Cb) Cb[row * MT + col] = f2b(v);
                s += v; s2 += v * v;
            }
        }
        if (osum) {
            s += __shfl_down(s, 32, 64);
            s2 += __shfl_down(s2, 32, 64);
            s += __shfl_down(s, 16, 64);
            s2 += __shfl_down(s2, 16, 64);
            if (lane < 16) {
                atomicAdd(&osum[col], s);
                atomicAdd(&osumsq[col], s2);
            }
        }
    }
}

extern "C" void kernel_launch(void* const* d_in, const int* in_sizes, int n_in,
                              void* d_out, int out_size, void* d_ws, size_t ws_size,
                              hipStream_t stream) {
    const float* x       = (const float*)d_in[0];
    const float* eattr   = (const float*)d_in[1];
    const int*   ei      = (const int*)d_in[2];
    const int*   lg      = (const int*)d_in[3];
    const int*   batch   = (const int*)d_in[4];
    const float* W_u     = (const float*)d_in[5];
    const float* W_v     = (const float*)d_in[6];
    const float* W_e     = (const float*)d_in[7];
    const float* gat_W   = (const float*)d_in[8];
    const float* att_s   = (const float*)d_in[9];
    const float* att_d   = (const float*)d_in[10];
    const float* gat_b   = (const float*)d_in[11];
    const float* a_att   = (const float*)d_in[12];
    const float* a_bias  = (const float*)d_in[13];
    const float* W_gout  = (const float*)d_in[14];
    const float* b_gout  = (const float*)d_in[15];
    const float* bn1_g   = (const float*)d_in[16];
    const float* bn1_b   = (const float*)d_in[17];
    const float* lb_W1   = (const float*)d_in[18];
    const float* lb_b1   = (const float*)d_in[19];
    const float* lb_bn_g = (const float*)d_in[20];
    const float* lb_bn_b = (const float*)d_in[21];
    const float* lb_pr   = (const float*)d_in[22];
    const float* lb_W    = (const float*)d_in[23];
    const float* lb_b    = (const float*)d_in[24];
    const float* bn5_g   = (const float*)d_in[25];
    const float* bn5_b   = (const float*)d_in[26];
    const float* pr5     = (const float*)d_in[27];
    const float* lb_W5   = (const float*)d_in[28];
    const float* lb_b5   = (const float*)d_in[29];
    float* out_final = (float*)d_out;

    // ---------------- workspace layout (~185 MB) ----------------
    const long long ESZ = (long long)EE * FF;
    const long long NSZ = (long long)NN * FF;
    char* cur = (char*)d_ws;
    auto alloc = [&](size_t bytes) -> void* {
        void* p = (void*)cur;
        cur += (bytes + 255) & ~(size_t)255;
        return p;
    };
    ushort_t* XU = (ushort_t*)alloc(NSZ * 2);
    ushort_t* XV = (ushort_t*)alloc(NSZ * 2);
    ushort_t* O1 = (ushort_t*)alloc(ESZ * 2);
    ushort_t* O2 = (ushort_t*)alloc(ESZ * 2);
    ushort_t* O3 = (ushort_t*)alloc(ESZ * 2);   // holds EAB until iter-3 overwrites it
    float* XW = (float*)alloc((size_t)EE * 4);
    float* XC = (float*)alloc((size_t)EE * 4);
    ushort_t* XNB = (ushort_t*)alloc(NSZ * 2);
    float* GRAW = (float*)alloc(BBATCH * FF * 4);
    float* G0 = (float*)alloc(BBATCH * FF * 4);
    float* G1 = (float*)alloc(BBATCH * FF * 4);
    float* G2 = (float*)alloc(BBATCH * FF * 4);
    float* SCATT = (float*)alloc(BBATCH * 3 * 4);
    int* BPTR = (int*)alloc((BBATCH + 1) * 4);
    int* LROW = (int*)alloc((size_t)(EE + 1) * 4);
    int* LSRC = (int*)alloc((size_t)LEE * 4);
    int* LCNT = (int*)alloc((size_t)EE * 4);
    int* NROW = (int*)alloc((size_t)(NN + 1) * 4);
    int* NIDX = (int*)alloc((size_t)EE * 4);
    int* NCNT = (int*)alloc((size_t)NN * 4);
    int* SP0 = (int*)alloc(2048 * 4);
    int* SP1 = (int*)alloc(256 * 4);
    float* STATS = (float*)alloc(5 * 2 * SFD * 4);   // 5 stages x (sum, sumsq)[384]
    if ((size_t)(cur - (char*)d_ws) > ws_size) return;  // diagnostic: zeros -> ws too small

    // LinBlock bf16 activations alias the O region (dead by then): 4 x 38.4 MB = 153.6 MB
    ushort_t* T1B = O1;                                  // lin1 out (x1)
    ushort_t* T2B = T1B + (long long)NN * SFD;           // lin2 out (h1)
    ushort_t* T3B = T2B + (long long)NN * SFD;           // lin3 out (x2)
    ushort_t* T4B = T3B + (long long)NN * SFD;           // lin4 out (x3)
    float* CS[5][2];
    for (int i = 0; i < 5; ++i) { CS[i][0] = STATS + i * 2 * SFD; CS[i][1] = CS[i][0] + SFD; }
    float* GTS[3] = {G0, G1, G2};

    // zero all stats accumulators once (harness poisons ws before every launch)
    hipMemsetAsync(STATS, 0, 5 * 2 * SFD * 4, stream);

    // 1. node transforms + batch rowptr
    k_node_mm<<<CDIV(NN, 4), 256, 0, stream>>>(x, W_u, W_v, XU, XV);
    k_batchptr<<<CDIV(EE, 256), 256, 0, stream>>>(batch, BPTR);

    // 2. build line-graph CSR (by dst)
    {
        hipMemsetAsync(LCNT, 0, (size_t)EE * 4, stream);
        k_hist<<<CDIV(LEE, 256), 256, 0, stream>>>(lg + LEE, LEE, LCNT);
        int nb0 = CDIV(EE, 256), nb1 = CDIV(nb0, 256);
        k_part<<<nb0, 256, 0, stream>>>(LCNT, EE, SP0);
        k_part<<<nb1, 256, 0, stream>>>(SP0, nb0, SP1);
        k_scan_single<<<1, 256, 0, stream>>>(SP1, nb1);
        k_scan_add<<<nb1, 256, 0, stream>>>(SP0, nb0, SP1);
        k_scan_out<<<nb0, 256, 0, stream>>>(LCNT, EE, SP0, LROW);
        hipMemsetAsync(LCNT, 0, (size_t)EE * 4, stream);
        k_fill_lg<<<CDIV(LEE, 256), 256, 0, stream>>>(lg, LROW, LCNT, LSRC);
    }
    // 3. build node CSR (by ei1)
    {
        hipMemsetAsync(NCNT, 0, (size_t)NN * 4, stream);
        k_hist<<<CDIV(EE, 256), 256, 0, stream>>>(ei + EE, EE, NCNT);
        int nb0 = CDIV(NN, 256), nb1 = CDIV(nb0, 256);
        k_part<<<nb0, 256, 0, stream>>>(NCNT, NN, SP0);
        k_part<<<nb1, 256, 0, stream>>>(SP0, nb0, SP1);
        k_scan_single<<<1, 256, 0, stream>>>(SP1, nb1);
        k_scan_add<<<nb1, 256, 0, stream>>>(SP0, nb0, SP1);
        k_scan_out<<<nb0, 256, 0, stream>>>(NCNT, NN, SP0, NROW);
        hipMemsetAsync(NCNT, 0, (size_t)NN * 4, stream);
        k_fill_n<<<CDIV(EE, 256), 256, 0, stream>>>(ei, NROW, NCNT, NIDX);
    }

    const int EB8 = CDIV(EE, 8);

    auto gat_pool = [&](ushort_t* buf, int t) {
        k_gat_fused<<<CDIV(EE, 256), 256, 0, stream>>>(XW, LROW, LSRC, att_s, att_d, gat_b, XC);
        k_pool<<<BBATCH, 256, 0, stream>>>(XC, buf, BPTR, GRAW);
        k_gout_mm<<<CDIV(BBATCH, 4), 256, 0, stream>>>(GRAW, W_gout, b_gout, GTS[t]);
    };

    // 4. EAB + message-passing iterations (uniform gathers, bf16 storage)
    k_ea_b16<<<EB8, 256, 0, stream>>>(XU, XV, eattr, W_e, ei, O3);              // O3 = EAB
    k_mp_gather<<<EB8, 256, 0, stream>>>(O3, O3, LROW, LSRC, gat_W, O1, XW);    // O1 = out1
    gat_pool(O1, 0);
    k_mp_gather<<<EB8, 256, 0, stream>>>(O1, O3, LROW, LSRC, gat_W, O2, XW);    // O2 = out2
    gat_pool(O2, 1);
    k_mp_gather<<<EB8, 256, 0, stream>>>(O2, O3, LROW, LSRC, gat_W, O3, XW);    // O3 = out3
    gat_pool(O3, 2);

    // 5. iteration attention + combine + node aggregation (writes bf16 XNB)
    k_att<<<BBATCH, 64, 0, stream>>>(G0, G1, G2, a_att, a_bias, SCATT);
    k_comb<<<(int)CDIV(ESZ, 256), 256, 0, stream>>>(O1, O2, O3, SCATT, batch);
    k_node_gather<<<CDIV(NN, 4), 256, 0, stream>>>(O1, NROW, NIDX, x, XNB);
    k_colstats_b16<<<256, FF, 0, stream>>>(XNB, FF, NN, CS[0][0], CS[0][1]);

    // 6. LinBlock: bf16 activation chain, stats fused into epilogues
    const int GB = CDIV(NN, 64);
    // lin1: x1 = bn1(xn) @ W1 + b1                       (K=64, no prelu)
    k_gemm_lb<384><<<GB, 512, 0, stream>>>(XNB, lb_W1, lb_b1, nullptr,
        CS[0][0], CS[0][1], bn1_g, bn1_b, nullptr, 1.0f, NN, FF,
        T1B, nullptr, CS[1][0], CS[1][1]);
    // lin2: h1 = prelu(bn(x1)) @ W[0] + b[0]
    k_gemm_lb<384><<<GB, 512, 0, stream>>>(T1B, lb_W, lb_b, nullptr,
        CS[1][0], CS[1][1], lb_bn_g, lb_bn_b, lb_pr, 1.0f, NN, SFD,
        T2B, nullptr, CS[2][0], CS[2][1]);
    // lin3: x2 = (prelu(bn(h1)) @ W[1] + b[1] + x1) / 2
    k_gemm_lb<384><<<GB, 512, 0, stream>>>(T2B, lb_W + (long long)SFD * SFD, lb_b + SFD, T1B,
        CS[2][0], CS[2][1], lb_bn_g + SFD, lb_bn_b + SFD, lb_pr + 1, 0.5f, NN, SFD,
        T3B, nullptr, CS[3][0], CS[3][1]);
    // lin4: x3 = (prelu(bn(x2)) @ W[2] + b[2] + x2) / 2
    k_gemm_lb<384><<<GB, 512, 0, stream>>>(T3B, lb_W + 2LL * SFD * SFD, lb_b + 2 * SFD, T3B,
        CS[3][0], CS[3][1], lb_bn_g + 2 * SFD, lb_bn_b + 2 * SFD, lb_pr + 2, 0.5f, NN, SFD,
        T4B, nullptr, CS[4][0], CS[4][1]);
    // lin5: out = prelu(bn5(x3)) @ W5 + b5              (f32 final output)
    k_gemm_lb<64><<<GB, 512, 0, stream>>>(T4B, lb_W5, lb_b5, nullptr,
        CS[4][0], CS[4][1], bn5_g, bn5_b, pr5, 1.0f, NN, SFD,
        nullptr, out_final, nullptr, nullptr);
}

// Round 7
// 2082.427 us; speedup vs baseline: 1.0585x; 1.0585x over previous
//
#include <hip/hip_runtime.h>
#include <math.h>

#define NN 50000
#define EE 400000
#define LEE 1600000
#define BBATCH 256
#define FF 64
#define EDD 16
#define NITER 3
#define SFD 384

#define CDIV(a,b) (((a)+(b)-1)/(b))

typedef unsigned short ushort_t;
typedef __attribute__((ext_vector_type(8))) short bf16x8;
typedef __attribute__((ext_vector_type(4))) float f32x4;

// ---------- helpers ----------
__device__ inline float b2f(ushort_t u) { return __uint_as_float(((unsigned)u) << 16); }
__device__ inline ushort_t f2b(float f) {   // RNE
    unsigned u = __float_as_uint(f);
    return (ushort_t)((u + 0x7fffu + ((u >> 16) & 1u)) >> 16);
}

// ---------- small CSR-build kernels ----------
__global__ void k_hist(const int* __restrict__ idx, int n, int* __restrict__ cnt) {
    int i = blockIdx.x * blockDim.x + threadIdx.x;
    if (i < n) atomicAdd(&cnt[idx[i]], 1);
}
__global__ void k_part(const int* __restrict__ in, int n, int* __restrict__ part) {
    __shared__ int s[256];
    int i = blockIdx.x * 256 + threadIdx.x;
    s[threadIdx.x] = (i < n) ? in[i] : 0;
    __syncthreads();
    for (int off = 128; off > 0; off >>= 1) {
        if (threadIdx.x < off) s[threadIdx.x] += s[threadIdx.x + off];
        __syncthreads();
    }
    if (threadIdx.x == 0) part[blockIdx.x] = s[0];
}
__global__ void k_scan_single(int* __restrict__ a, int n) {
    __shared__ int s[256];
    int v = (threadIdx.x < n) ? a[threadIdx.x] : 0;
    s[threadIdx.x] = v; __syncthreads();
    for (int off = 1; off < 256; off <<= 1) {
        int t = (threadIdx.x >= off) ? s[threadIdx.x - off] : 0;
        __syncthreads(); s[threadIdx.x] += t; __syncthreads();
    }
    if (threadIdx.x < n) a[threadIdx.x] = s[threadIdx.x] - v;
}
__global__ void k_scan_add(int* __restrict__ a, int n, const int* __restrict__ off) {
    __shared__ int s[256];
    int i = blockIdx.x * 256 + threadIdx.x;
    int v = (i < n) ? a[i] : 0;
    s[threadIdx.x] = v; __syncthreads();
    for (int o = 1; o < 256; o <<= 1) {
        int t = (threadIdx.x >= o) ? s[threadIdx.x - o] : 0;
        __syncthreads(); s[threadIdx.x] += t; __syncthreads();
    }
    if (i < n) a[i] = s[threadIdx.x] - v + off[blockIdx.x];
}
__global__ void k_scan_out(const int* __restrict__ in, int n, const int* __restrict__ boff,
                           int* __restrict__ out) {
    __shared__ int s[256];
    int i = blockIdx.x * 256 + threadIdx.x;
    int v = (i < n) ? in[i] : 0;
    s[threadIdx.x] = v; __syncthreads();
    for (int o = 1; o < 256; o <<= 1) {
        int t = (threadIdx.x >= o) ? s[threadIdx.x - o] : 0;
        __syncthreads(); s[threadIdx.x] += t; __syncthreads();
    }
    if (i < n) out[i] = s[threadIdx.x] - v + boff[blockIdx.x];
    if (i == n - 1) out[n] = s[threadIdx.x] + boff[blockIdx.x];
}
__global__ void k_fill_lg(const int* __restrict__ lg, const int* __restrict__ rowptr,
                          int* __restrict__ cnt, int* __restrict__ srcidx) {
    int i = blockIdx.x * blockDim.x + threadIdx.x;
    if (i >= LEE) return;
    int d = lg[LEE + i];
    int pos = rowptr[d] + atomicAdd(&cnt[d], 1);
    srcidx[pos] = lg[i];
}
__global__ void k_fill_n(const int* __restrict__ ei, const int* __restrict__ rowptr,
                         int* __restrict__ cnt, int* __restrict__ nidx) {
    int i = blockIdx.x * blockDim.x + threadIdx.x;
    if (i >= EE) return;
    int d = ei[EE + i];
    int pos = rowptr[d] + atomicAdd(&cnt[d], 1);
    nidx[pos] = i;
}

// ---------- main kernels ----------

// xu = bf16(x @ W_u), xv = bf16(x @ W_v)
__global__ void k_node_mm(const float* __restrict__ x, const float* __restrict__ Wu,
                          const float* __restrict__ Wv, ushort_t* __restrict__ xu,
                          ushort_t* __restrict__ xv) {
    __shared__ float su[64 * 64];
    __shared__ float sv[64 * 64];
    int tid = threadIdx.x;
    for (int i = tid; i < 64 * 64; i += blockDim.x) { su[i] = Wu[i]; sv[i] = Wv[i]; }
    __syncthreads();
    int row = blockIdx.x * 4 + (tid >> 6);
    int f = tid & 63;
    if (row >= NN) return;
    const float* xr = x + (long long)row * 64;
    float au = 0.f, av = 0.f;
    #pragma unroll
    for (int k = 0; k < 64; ++k) {
        float xv_ = xr[k];
        au += xv_ * su[k * 64 + f];
        av += xv_ * sv[k * 64 + f];
    }
    xu[(long long)row * 64 + f] = f2b(au);
    xv[(long long)row * 64 + f] = f2b(av);
}

// eab[e][f] = bf16((xu[ei0] + xv[ei1] + eattr @ W_e)/3); 2 feats/lane, 2 edges/wave
__global__ void k_ea_b16(const ushort_t* __restrict__ xu, const ushort_t* __restrict__ xv,
                         const float* __restrict__ eattr, const float* __restrict__ We,
                         const int* __restrict__ ei, ushort_t* __restrict__ eab) {
    __shared__ float swe[16 * 64];
    int tid = threadIdx.x;
    for (int i = tid; i < 1024; i += 256) swe[i] = We[i];
    __syncthreads();
    int e = blockIdx.x * 8 + (tid >> 5);
    int f2 = (tid & 31) * 2;
    if (e >= EE) return;
    int s = ei[e];
    int d = ei[EE + e];
    unsigned us = *(const unsigned*)&xu[(long long)s * 64 + f2];
    unsigned ud = *(const unsigned*)&xv[(long long)d * 64 + f2];
    const float* ar = eattr + (long long)e * 16;
    float a0 = 0.f, a1 = 0.f;
    #pragma unroll
    for (int k = 0; k < 16; ++k) {
        float w = ar[k];
        a0 += w * swe[k * 64 + f2];
        a1 += w * swe[k * 64 + f2 + 1];
    }
    float v0 = (b2f((ushort_t)us) + b2f((ushort_t)ud) + a0) * (1.0f / 3.0f);
    float v1 = (b2f((ushort_t)(us >> 16)) + b2f((ushort_t)(ud >> 16)) + a1) * (1.0f / 3.0f);
    *(unsigned*)&eab[(long long)e * 64 + f2] = (unsigned)f2b(v0) | ((unsigned)f2b(v1) << 16);
}

// out[d] = eab[d] + sum_{src} prev[src]; xw[d] = out[d].gatW. 2 feats/lane, 2 edges/wave
__global__ void k_mp_gather(const ushort_t* __restrict__ prev,
                            const ushort_t* __restrict__ eab,
                            const int* __restrict__ rowptr, const int* __restrict__ srcidx,
                            const float* __restrict__ gatW,
                            ushort_t* __restrict__ outb, float* __restrict__ xw) {
    int tid = threadIdx.x;
    int d = blockIdx.x * 8 + (tid >> 5);
    int f2 = (tid & 31) * 2;
    if (d >= EE) return;
    unsigned ue = *(const unsigned*)&eab[(long long)d * 64 + f2];
    float a0 = b2f((ushort_t)ue), a1 = b2f((ushort_t)(ue >> 16));
    int p0 = rowptr[d], p1 = rowptr[d + 1];
    int j = p0;
    for (; j + 4 <= p1; j += 4) {
        int s0 = srcidx[j], s1 = srcidx[j + 1], s2 = srcidx[j + 2], s3 = srcidx[j + 3];
        unsigned u0 = *(const unsigned*)&prev[(long long)s0 * 64 + f2];
        unsigned u1 = *(const unsigned*)&prev[(long long)s1 * 64 + f2];
        unsigned u2 = *(const unsigned*)&prev[(long long)s2 * 64 + f2];
        unsigned u3 = *(const unsigned*)&prev[(long long)s3 * 64 + f2];
        a0 += (b2f((ushort_t)u0) + b2f((ushort_t)u1)) + (b2f((ushort_t)u2) + b2f((ushort_t)u3));
        a1 += (b2f((ushort_t)(u0 >> 16)) + b2f((ushort_t)(u1 >> 16))) +
              (b2f((ushort_t)(u2 >> 16)) + b2f((ushort_t)(u3 >> 16)));
    }
    for (; j < p1; ++j) {
        unsigned u0 = *(const unsigned*)&prev[(long long)srcidx[j] * 64 + f2];
        a0 += b2f((ushort_t)u0);
        a1 += b2f((ushort_t)(u0 >> 16));
    }
    *(unsigned*)&outb[(long long)d * 64 + f2] = (unsigned)f2b(a0) | ((unsigned)f2b(a1) << 16);
    float w = a0 * gatW[f2] + a1 * gatW[f2 + 1];
    #pragma unroll
    for (int o = 16; o > 0; o >>= 1) w += __shfl_down(w, o, 32);
    if ((tid & 31) == 0) xw[d] = w;
}

// fused GAT: per dst edge, serial max / exp-sum / weighted-sum over CSR in-edges + self-loop
__global__ void k_gat_fused(const float* __restrict__ xw,
                            const int* __restrict__ rowptr, const int* __restrict__ srcidx,
                            const float* __restrict__ att_s, const float* __restrict__ att_d,
                            const float* __restrict__ gbias, float* __restrict__ xc) {
    int e = blockIdx.x * blockDim.x + threadIdx.x;
    if (e >= EE) return;
    float as = att_s[0], ad = att_d[0];
    float xwd = xw[e];
    float adt = xwd * ad;
    float aself = xwd * as + adt;
    if (aself < 0.f) aself *= 0.2f;
    int p0 = rowptr[e], p1 = rowptr[e + 1];
    float m = aself;
    for (int j = p0; j < p1; ++j) {
        float a = xw[srcidx[j]] * as + adt;
        if (a < 0.f) a *= 0.2f;
        m = fmaxf(m, a);
    }
    float ssum = expf(aself - m);
    float wsum = ssum * xwd;
    for (int j = p0; j < p1; ++j) {
        float xs = xw[srcidx[j]];
        float a = xs * as + adt;
        if (a < 0.f) a *= 0.2f;
        float ev = expf(a - m);
        ssum += ev;
        wsum += ev * xs;
    }
    xc[e] = wsum / (ssum + 1e-16f) + gbias[0];
}

__global__ void k_batchptr(const int* __restrict__ batch, int* __restrict__ bptr) {
    int e = blockIdx.x * blockDim.x + threadIdx.x;
    if (e >= EE) return;
    int b = batch[e];
    int bp = (e == 0) ? -1 : batch[e - 1];
    for (int q = bp + 1; q <= b; ++q) bptr[q] = e;
    if (e == EE - 1)
        for (int q = b + 1; q <= BBATCH; ++q) bptr[q] = EE;
}

// per-batch: softmax(xc) over segment, weighted-sum pool of bf16 out
__global__ void k_pool(const float* __restrict__ xc, const ushort_t* __restrict__ out,
                       const int* __restrict__ bptr, float* __restrict__ gout) {
    int b = blockIdx.x;
    int p0 = bptr[b], p1 = bptr[b + 1];
    __shared__ float red[256];
    int tid = threadIdx.x;
    float mx = -INFINITY;
    for (int e = p0 + tid; e < p1; e += 256) mx = fmaxf(mx, xc[e]);
    red[tid] = mx; __syncthreads();
    for (int s = 128; s > 0; s >>= 1) { if (tid < s) red[tid] = fmaxf(red[tid], red[tid + s]); __syncthreads(); }
    float m = red[0]; __syncthreads();
    float sm = 0.f;
    for (int e = p0 + tid; e < p1; e += 256) sm += expf(xc[e] - m);
    red[tid] = sm; __syncthreads();
    for (int s = 128; s > 0; s >>= 1) { if (tid < s) red[tid] += red[tid + s]; __syncthreads(); }
    float ssum = red[0] + 1e-16f; __syncthreads();
    int f = tid & 63, chunk = tid >> 6;
    float acc = 0.f;
    for (int e = p0 + chunk; e < p1; e += 4) {
        float w = expf(xc[e] - m);
        acc += w * b2f(out[(long long)e * 64 + f]);
    }
    red[tid] = acc; __syncthreads();
    if (chunk == 0) {
        float tot = red[f] + red[64 + f] + red[128 + f] + red[192 + f];
        gout[b * 64 + f] = tot / ssum;
    }
}

__global__ void k_gout_mm(const float* __restrict__ gout, const float* __restrict__ Wg,
                          const float* __restrict__ bg, float* __restrict__ gt) {
    __shared__ float sw[64 * 64];
    int tid = threadIdx.x;
    for (int i = tid; i < 4096; i += blockDim.x) sw[i] = Wg[i];
    __syncthreads();
    int row = blockIdx.x * 4 + (tid >> 6);
    int f = tid & 63;
    if (row >= BBATCH) return;
    const float* gr = gout + row * 64;
    float acc = bg[f];
    #pragma unroll
    for (int k = 0; k < 64; ++k) acc += gr[k] * sw[k * 64 + f];
    gt[row * 64 + f] = tanhf(acc);
}

__global__ void k_att(const float* __restrict__ g0, const float* __restrict__ g1,
                      const float* __restrict__ g2, const float* __restrict__ a,
                      const float* __restrict__ abias, float* __restrict__ sc) {
    int b = blockIdx.x;
    int f = threadIdx.x; // 64 threads
    float v0 = g0[b * 64 + f] * a[f * 3 + 0];
    float v1 = g1[b * 64 + f] * a[f * 3 + 1];
    float v2 = g2[b * 64 + f] * a[f * 3 + 2];
    #pragma unroll
    for (int o = 32; o > 0; o >>= 1) {
        v0 += __shfl_down(v0, o, 64);
        v1 += __shfl_down(v1, o, 64);
        v2 += __shfl_down(v2, o, 64);
    }
    if (f == 0) {
        float s0 = v0 + abias[0], s1 = v1 + abias[1], s2 = v2 + abias[2];
        float m = fmaxf(s0, fmaxf(s1, s2));
        float e0 = expf(s0 - m), e1 = expf(s1 - m), e2 = expf(s2 - m);
        float inv = 1.0f / (e0 + e1 + e2);
        sc[b * 3 + 0] = e0 * inv; sc[b * 3 + 1] = e1 * inv; sc[b * 3 + 2] = e2 * inv;
    }
}

// o1 <- sum_t o_t * sc_t[batch]   (elementwise, in place on o1)
__global__ void k_comb(ushort_t* __restrict__ o1, const ushort_t* __restrict__ o2,
                       const ushort_t* __restrict__ o3, const float* __restrict__ sc,
                       const int* __restrict__ batch) {
    long long idx = (long long)blockIdx.x * blockDim.x + threadIdx.x;
    if (idx >= (long long)EE * 64) return;
    int e = (int)(idx >> 6);
    int b = batch[e];
    float v = b2f(o1[idx]) * sc[b * 3] + b2f(o2[idx]) * sc[b * 3 + 1] + b2f(o3[idx]) * sc[b * 3 + 2];
    o1[idx] = f2b(v);
}

// xnb[n] = bf16(x[n] + sum over in-edges of comb[e])
__global__ void k_node_gather(const ushort_t* __restrict__ comb, const int* __restrict__ nrow,
                              const int* __restrict__ nidx, const float* __restrict__ x,
                              ushort_t* __restrict__ xnb) {
    int tid = threadIdx.x;
    int n = blockIdx.x * 4 + (tid >> 6);
    int f = tid & 63;
    if (n >= NN) return;
    float acc = x[(long long)n * 64 + f];
    int p0 = nrow[n], p1 = nrow[n + 1];
    int j = p0;
    for (; j + 4 <= p1; j += 4) {
        int e0 = nidx[j], e1 = nidx[j + 1], e2 = nidx[j + 2], e3 = nidx[j + 3];
        float v0 = b2f(comb[(long long)e0 * 64 + f]);
        float v1 = b2f(comb[(long long)e1 * 64 + f]);
        float v2 = b2f(comb[(long long)e2 * 64 + f]);
        float v3 = b2f(comb[(long long)e3 * 64 + f]);
        acc += (v0 + v1) + (v2 + v3);
    }
    for (; j < p1; ++j) acc += b2f(comb[(long long)nidx[j] * 64 + f]);
    xnb[(long long)n * 64 + f] = f2b(acc);
}

// column stats of a bf16 matrix (blockDim.x == ncols)
__global__ void k_colstats_b16(const ushort_t* __restrict__ X, int ncols, int nrows,
                               float* __restrict__ csum, float* __restrict__ csumsq) {
    int c = threadIdx.x;
    int rpb = CDIV(nrows, (int)gridDim.x);
    int r0 = blockIdx.x * rpb;
    int r1 = min(r0 + rpb, nrows);
    float s = 0.f, s2 = 0.f;
    for (int r = r0; r < r1; ++r) {
        float v = b2f(X[(long long)r * ncols + c]);
        s += v; s2 += v * v;
    }
    atomicAdd(&csum[c], s);
    atomicAdd(&csumsq[c], s2);
}

// LDS-tiled transpose+convert: W [K,M] f32 -> Wt [M,K] bf16
__global__ void k_wtrans(const float* __restrict__ W, int K, int M, ushort_t* __restrict__ Wt) {
    __shared__ ushort_t tile[32][33];
    int kb = blockIdx.y * 32, mb = blockIdx.x * 32;
    int tx = threadIdx.x & 31, ty = threadIdx.x >> 5;   // 256 threads: ty 0..7
    for (int dy = ty; dy < 32; dy += 8) {
        int k = kb + dy, m = mb + tx;
        tile[dy][tx] = (k < K && m < M) ? f2b(W[(long long)k * M + m]) : (ushort_t)0;
    }
    __syncthreads();
    for (int dy = ty; dy < 32; dy += 8) {
        int m = mb + dy, k = kb + tx;
        if (m < M && k < K) Wt[(long long)m * K + k] = tile[tx][dy];
    }
}

// LinBlock GEMM: C = scale*(act(bn(A)) @ W + bias + res)
// A bf16 [nrows,KK] staged via LDS (BN+PReLU fused); Wt bf16 [M,KK] read direct
// from global (L2-resident). Block tile (WR*64) x (WC*64), 4 waves, each wave
// 64x64 via 4x4 16x16x32 frags. Output stats fused (wave-reduced atomics).
template<int KK, int WR, int WC>
__global__ __launch_bounds__(256) void k_gemm_fused(
    const ushort_t* __restrict__ A, const ushort_t* __restrict__ Wt,
    const float* __restrict__ bias, const ushort_t* __restrict__ resb,
    const float* __restrict__ csum, const float* __restrict__ csumsq,
    const float* __restrict__ g, const float* __restrict__ bb,
    const float* __restrict__ pr, float scale, int nrows, int M,
    ushort_t* __restrict__ Cb, float* __restrict__ Cf,
    float* __restrict__ osum, float* __restrict__ osumsq) {
    constexpr int RT = WR * 64;
    __shared__ ushort_t sA[RT][36];      // 72B row stride: b64 accesses hit uniform banks
    __shared__ float sScl[KK], sOff[KK];
    int tid = threadIdx.x;
    int wave = tid >> 6, lane = tid & 63;
    int l16 = lane & 15, klo = lane >> 4;
    int wrow = wave / WC, wcol = wave % WC;
    long long rowBase = (long long)blockIdx.x * RT;
    int colBase = blockIdx.y * (WC * 64);
    float prs = pr ? pr[0] : 1.0f;
    const float invn = 1.0f / (float)NN;
    for (int c = tid; c < KK; c += 256) {
        float mean = csum[c] * invn;
        float var = csumsq[c] * invn - mean * mean;
        float scl = rsqrtf(var + 1e-5f) * g[c];
        sScl[c] = scl;
        sOff[c] = bb[c] - mean * scl;
    }
    __syncthreads();
    f32x4 acc[4][4] = {};
    for (int k0 = 0; k0 < KK; k0 += 32) {
        // stage A: RT rows x 32 k, 8 elems (16B) per thread per iter, BN+act fused
        #pragma unroll
        for (int it = 0; it < RT * 32 / (256 * 8); ++it) {
            int idx = (it * 256 + tid) * 8;
            int r = idx >> 5, kk = idx & 31;
            long long gr = rowBase + r;
            uint4 raw = {0u, 0u, 0u, 0u};
            if (gr < nrows) raw = *(const uint4*)&A[gr * KK + k0 + kk];
            unsigned outw[4];
            #pragma unroll
            for (int q = 0; q < 4; ++q) {
                unsigned rw = ((const unsigned*)&raw)[q];
                int c = k0 + kk + q * 2;
                float t0 = b2f((ushort_t)rw) * sScl[c] + sOff[c];
                float t1 = b2f((ushort_t)(rw >> 16)) * sScl[c + 1] + sOff[c + 1];
                if (t0 < 0.f) t0 *= prs;
                if (t1 < 0.f) t1 *= prs;
                outw[q] = (unsigned)f2b(t0) | ((unsigned)f2b(t1) << 16);
            }
            uint2 w0; w0.x = outw[0]; w0.y = outw[1];
            uint2 w1; w1.x = outw[2]; w1.y = outw[3];
            *(uint2*)&sA[r][kk] = w0;
            *(uint2*)&sA[r][kk + 4] = w1;
        }
        __syncthreads();
        // B frags direct from global Wt[col][k] (L2-resident)
        bf16x8 bfr[4];
        #pragma unroll
        for (int n = 0; n < 4; ++n) {
            int col = colBase + wcol * 64 + n * 16 + l16;
            bfr[n] = *(const bf16x8*)&Wt[(long long)col * KK + k0 + klo * 8];
        }
        // A frags from LDS (2 x b64 each)
        bf16x8 afr[4];
        #pragma unroll
        for (int m = 0; m < 4; ++m) {
            union { uint2 p[2]; bf16x8 v; } u;
            int row = wrow * 64 + m * 16 + l16;
            u.p[0] = *(const uint2*)&sA[row][klo * 8];
            u.p[1] = *(const uint2*)&sA[row][klo * 8 + 4];
            afr[m] = u.v;
        }
        #pragma unroll
        for (int m = 0; m < 4; ++m)
            #pragma unroll
            for (int n = 0; n < 4; ++n)
                acc[m][n] = __builtin_amdgcn_mfma_f32_16x16x32_bf16(afr[m], bfr[n], acc[m][n], 0, 0, 0);
        __syncthreads();
    }
    // epilogue: C/D col=lane&15, row=(lane>>4)*4+reg; fused bias/res/scale/stats
    #pragma unroll
    for (int m = 0; m < 4; ++m) {
        #pragma unroll
        for (int n = 0; n < 4; ++n) {
            int col = colBase + wcol * 64 + n * 16 + l16;
            long long row0 = rowBase + wrow * 64 + m * 16 + klo * 4;
            float bcol = bias[col];
            float s = 0.f, s2 = 0.f;
            #pragma unroll
            for (int r = 0; r < 4; ++r) {
                long long row = row0 + r;
                if (row < nrows) {
                    float v = acc[m][n][r] + bcol;
                    if (resb) v += b2f(resb[row * M + col]);
                    v *= scale;
                    if (Cf) Cf[row * M + col] = v;
                    if (Cb) Cb[row * M + col] = f2b(v);
                    s += v; s2 += v * v;
                }
            }
            if (osum) {
                s += __shfl_down(s, 32, 64);
                s2 += __shfl_down(s2, 32, 64);
                s += __shfl_down(s, 16, 64);
                s2 += __shfl_down(s2, 16, 64);
                if (lane < 16) {
                    atomicAdd(&osum[col], s);
                    atomicAdd(&osumsq[col], s2);
                }
            }
        }
    }
}

extern "C" void kernel_launch(void* const* d_in, const int* in_sizes, int n_in,
                              void* d_out, int out_size, void* d_ws, size_t ws_size,
                              hipStream_t stream) {
    const float* x       = (const float*)d_in[0];
    const float* eattr   = (const float*)d_in[1];
    const int*   ei      = (const int*)d_in[2];
    const int*   lg      = (const int*)d_in[3];
    const int*   batch   = (const int*)d_in[4];
    const float* W_u     = (const float*)d_in[5];
    const float* W_v     = (const float*)d_in[6];
    const float* W_e     = (const float*)d_in[7];
    const float* gat_W   = (const float*)d_in[8];
    const float* att_s   = (const float*)d_in[9];
    const float* att_d   = (const float*)d_in[10];
    const float* gat_b   = (const float*)d_in[11];
    const float* a_att   = (const float*)d_in[12];
    const float* a_bias  = (const float*)d_in[13];
    const float* W_gout  = (const float*)d_in[14];
    const float* b_gout  = (const float*)d_in[15];
    const float* bn1_g   = (const float*)d_in[16];
    const float* bn1_b   = (const float*)d_in[17];
    const float* lb_W1   = (const float*)d_in[18];
    const float* lb_b1   = (const float*)d_in[19];
    const float* lb_bn_g = (const float*)d_in[20];
    const float* lb_bn_b = (const float*)d_in[21];
    const float* lb_pr   = (const float*)d_in[22];
    const float* lb_W    = (const float*)d_in[23];
    const float* lb_b    = (const float*)d_in[24];
    const float* bn5_g   = (const float*)d_in[25];
    const float* bn5_b   = (const float*)d_in[26];
    const float* pr5     = (const float*)d_in[27];
    const float* lb_W5   = (const float*)d_in[28];
    const float* lb_b5   = (const float*)d_in[29];
    float* out_final = (float*)d_out;

    // ---------------- workspace layout (~186 MB) ----------------
    const long long ESZ = (long long)EE * FF;
    const long long NSZ = (long long)NN * FF;
    char* cur = (char*)d_ws;
    auto alloc = [&](size_t bytes) -> void* {
        void* p = (void*)cur;
        cur += (bytes + 255) & ~(size_t)255;
        return p;
    };
    ushort_t* XU = (ushort_t*)alloc(NSZ * 2);
    ushort_t* XV = (ushort_t*)alloc(NSZ * 2);
    ushort_t* O1 = (ushort_t*)alloc(ESZ * 2);
    ushort_t* O2 = (ushort_t*)alloc(ESZ * 2);
    ushort_t* O3 = (ushort_t*)alloc(ESZ * 2);   // holds EAB until iter-3 overwrites it
    float* XW = (float*)alloc((size_t)EE * 4);
    float* XC = (float*)alloc((size_t)EE * 4);
    ushort_t* XNB = (ushort_t*)alloc(NSZ * 2);
    float* GRAW = (float*)alloc(BBATCH * FF * 4);
    float* G0 = (float*)alloc(BBATCH * FF * 4);
    float* G1 = (float*)alloc(BBATCH * FF * 4);
    float* G2 = (float*)alloc(BBATCH * FF * 4);
    float* SCATT = (float*)alloc(BBATCH * 3 * 4);
    int* BPTR = (int*)alloc((BBATCH + 1) * 4);
    int* LROW = (int*)alloc((size_t)(EE + 1) * 4);
    int* LSRC = (int*)alloc((size_t)LEE * 4);
    int* LCNT = (int*)alloc((size_t)EE * 4);
    int* NROW = (int*)alloc((size_t)(NN + 1) * 4);
    int* NIDX = (int*)alloc((size_t)EE * 4);
    int* NCNT = (int*)alloc((size_t)NN * 4);
    int* SP0 = (int*)alloc(2048 * 4);
    int* SP1 = (int*)alloc(256 * 4);
    float* STATS = (float*)alloc(5 * 2 * SFD * 4);   // 5 stages x (sum, sumsq)[384]
    ushort_t* WT1 = (ushort_t*)alloc((size_t)SFD * FF * 2);       // [384][64]
    ushort_t* WT2 = (ushort_t*)alloc((size_t)SFD * SFD * 2);      // [384][384]
    ushort_t* WT3 = (ushort_t*)alloc((size_t)SFD * SFD * 2);
    ushort_t* WT4 = (ushort_t*)alloc((size_t)SFD * SFD * 2);
    ushort_t* WT5 = (ushort_t*)alloc((size_t)FF * SFD * 2);       // [64][384]
    if ((size_t)(cur - (char*)d_ws) > ws_size) return;  // diagnostic: zeros -> ws too small

    // LinBlock bf16 activations alias the O region (dead by then): 4 x 38.4 MB = 153.6 MB
    ushort_t* T1B = O1;
    ushort_t* T2B = T1B + (long long)NN * SFD;
    ushort_t* T3B = T2B + (long long)NN * SFD;
    ushort_t* T4B = T3B + (long long)NN * SFD;
    float* CS[5][2];
    for (int i = 0; i < 5; ++i) { CS[i][0] = STATS + i * 2 * SFD; CS[i][1] = CS[i][0] + SFD; }
    float* GTS[3] = {G0, G1, G2};

    hipMemsetAsync(STATS, 0, 5 * 2 * SFD * 4, stream);

    // 0. weight transpose+convert (bf16 [col][k]), once per launch
    {
        dim3 gt(SFD / 32, FF / 32);
        k_wtrans<<<gt, 256, 0, stream>>>(lb_W1, FF, SFD, WT1);
        dim3 gs(SFD / 32, SFD / 32);
        k_wtrans<<<gs, 256, 0, stream>>>(lb_W, SFD, SFD, WT2);
        k_wtrans<<<gs, 256, 0, stream>>>(lb_W + (long long)SFD * SFD, SFD, SFD, WT3);
        k_wtrans<<<gs, 256, 0, stream>>>(lb_W + 2LL * SFD * SFD, SFD, SFD, WT4);
        dim3 g5(FF / 32, SFD / 32);
        k_wtrans<<<g5, 256, 0, stream>>>(lb_W5, SFD, FF, WT5);
    }

    // 1. node transforms + batch rowptr
    k_node_mm<<<CDIV(NN, 4), 256, 0, stream>>>(x, W_u, W_v, XU, XV);
    k_batchptr<<<CDIV(EE, 256), 256, 0, stream>>>(batch, BPTR);

    // 2. build line-graph CSR (by dst)
    {
        hipMemsetAsync(LCNT, 0, (size_t)EE * 4, stream);
        k_hist<<<CDIV(LEE, 256), 256, 0, stream>>>(lg + LEE, LEE, LCNT);
        int nb0 = CDIV(EE, 256), nb1 = CDIV(nb0, 256);
        k_part<<<nb0, 256, 0, stream>>>(LCNT, EE, SP0);
        k_part<<<nb1, 256, 0, stream>>>(SP0, nb0, SP1);
        k_scan_single<<<1, 256, 0, stream>>>(SP1, nb1);
        k_scan_add<<<nb1, 256, 0, stream>>>(SP0, nb0, SP1);
        k_scan_out<<<nb0, 256, 0, stream>>>(LCNT, EE, SP0, LROW);
        hipMemsetAsync(LCNT, 0, (size_t)EE * 4, stream);
        k_fill_lg<<<CDIV(LEE, 256), 256, 0, stream>>>(lg, LROW, LCNT, LSRC);
    }
    // 3. build node CSR (by ei1)
    {
        hipMemsetAsync(NCNT, 0, (size_t)NN * 4, stream);
        k_hist<<<CDIV(EE, 256), 256, 0, stream>>>(ei + EE, EE, NCNT);
        int nb0 = CDIV(NN, 256), nb1 = CDIV(nb0, 256);
        k_part<<<nb0, 256, 0, stream>>>(NCNT, NN, SP0);
        k_part<<<nb1, 256, 0, stream>>>(SP0, nb0, SP1);
        k_scan_single<<<1, 256, 0, stream>>>(SP1, nb1);
        k_scan_add<<<nb1, 256, 0, stream>>>(SP0, nb0, SP1);
        k_scan_out<<<nb0, 256, 0, stream>>>(NCNT, NN, SP0, NROW);
        hipMemsetAsync(NCNT, 0, (size_t)NN * 4, stream);
        k_fill_n<<<CDIV(EE, 256), 256, 0, stream>>>(ei, NROW, NCNT, NIDX);
    }

    const int EB8 = CDIV(EE, 8);

    auto gat_pool = [&](ushort_t* buf, int t) {
        k_gat_fused<<<CDIV(EE, 256), 256, 0, stream>>>(XW, LROW, LSRC, att_s, att_d, gat_b, XC);
        k_pool<<<BBATCH, 256, 0, stream>>>(XC, buf, BPTR, GRAW);
        k_gout_mm<<<CDIV(BBATCH, 4), 256, 0, stream>>>(GRAW, W_gout, b_gout, GTS[t]);
    };

    // 4. EAB + message-passing iterations (uniform gathers, bf16 storage)
    k_ea_b16<<<EB8, 256, 0, stream>>>(XU, XV, eattr, W_e, ei, O3);              // O3 = EAB
    k_mp_gather<<<EB8, 256, 0, stream>>>(O3, O3, LROW, LSRC, gat_W, O1, XW);    // O1 = out1
    gat_pool(O1, 0);
    k_mp_gather<<<EB8, 256, 0, stream>>>(O1, O3, LROW, LSRC, gat_W, O2, XW);    // O2 = out2
    gat_pool(O2, 1);
    k_mp_gather<<<EB8, 256, 0, stream>>>(O2, O3, LROW, LSRC, gat_W, O3, XW);    // O3 = out3
    gat_pool(O3, 2);

    // 5. iteration attention + combine + node aggregation (writes bf16 XNB)
    k_att<<<BBATCH, 64, 0, stream>>>(G0, G1, G2, a_att, a_bias, SCATT);
    k_comb<<<(int)CDIV(ESZ, 256), 256, 0, stream>>>(O1, O2, O3, SCATT, batch);
    k_node_gather<<<CDIV(NN, 4), 256, 0, stream>>>(O1, NROW, NIDX, x, XNB);
    k_colstats_b16<<<256, FF, 0, stream>>>(XNB, FF, NN, CS[0][0], CS[0][1]);

    // 6. LinBlock: MFMA GEMMs, BN fused, stats fused into epilogues
    {
        dim3 g(CDIV(NN, 128), SFD / 128);   // 391 x 3
        // lin1: x1 = bn1(xn) @ W1 + b1    (K=64, no prelu)
        k_gemm_fused<64, 2, 2><<<g, 256, 0, stream>>>(XNB, WT1, lb_b1, nullptr,
            CS[0][0], CS[0][1], bn1_g, bn1_b, nullptr, 1.0f, NN, SFD,
            T1B, nullptr, CS[1][0], CS[1][1]);
        // lin2: h1 = prelu(bn(x1)) @ W[0] + b[0]
        k_gemm_fused<384, 2, 2><<<g, 256, 0, stream>>>(T1B, WT2, lb_b, nullptr,
            CS[1][0], CS[1][1], lb_bn_g, lb_bn_b, lb_pr, 1.0f, NN, SFD,
            T2B, nullptr, CS[2][0], CS[2][1]);
        // lin3: x2 = (prelu(bn(h1)) @ W[1] + b[1] + x1) / 2
        k_gemm_fused<384, 2, 2><<<g, 256, 0, stream>>>(T2B, WT3, lb_b + SFD, T1B,
            CS[2][0], CS[2][1], lb_bn_g + SFD, lb_bn_b + SFD, lb_pr + 1, 0.5f, NN, SFD,
            T3B, nullptr, CS[3][0], CS[3][1]);
        // lin4: x3 = (prelu(bn(x2)) @ W[2] + b[2] + x2) / 2
        k_gemm_fused<384, 2, 2><<<g, 256, 0, stream>>>(T3B, WT4, lb_b + 2 * SFD, T3B,
            CS[3][0], CS[3][1], lb_bn_g + 2 * SFD, lb_bn_b + 2 * SFD, lb_pr + 2, 0.5f, NN, SFD,
            T4B, nullptr, CS[4][0], CS[4][1]);
        // lin5: out = prelu(bn5(x3)) @ W5 + b5    (f32 out, 256x64 tile)
        dim3 g5(CDIV(NN, 256), 1);
        k_gemm_fused<384, 4, 1><<<g5, 256, 0, stream>>>(T4B, WT5, lb_b5, nullptr,
            CS[4][0], CS[4][1], bn5_g, bn5_b, pr5, 1.0f, NN, FF,
            nullptr, out_final, nullptr, nullptr);
    }
}

// Round 8
// 1998.168 us; speedup vs baseline: 1.1031x; 1.0422x over previous
//
#include <hip/hip_runtime.h>
#include <math.h>

#define NN 50000
#define EE 400000
#define LEE 1600000
#define BBATCH 256
#define FF 64
#define EDD 16
#define NITER 3
#define SFD 384

#define CDIV(a,b) (((a)+(b)-1)/(b))

typedef unsigned short ushort_t;
typedef __attribute__((ext_vector_type(8))) short bf16x8;
typedef __attribute__((ext_vector_type(4))) float f32x4;

// ---------- helpers ----------
__device__ inline float b2f(ushort_t u) { return __uint_as_float(((unsigned)u) << 16); }
__device__ inline ushort_t f2b(float f) {   // RNE
    unsigned u = __float_as_uint(f);
    return (ushort_t)((u + 0x7fffu + ((u >> 16) & 1u)) >> 16);
}

// ---------- small CSR-build kernels ----------
__global__ void k_hist(const int* __restrict__ idx, int n, int* __restrict__ cnt) {
    int i = blockIdx.x * blockDim.x + threadIdx.x;
    if (i < n) atomicAdd(&cnt[idx[i]], 1);
}
__global__ void k_part(const int* __restrict__ in, int n, int* __restrict__ part) {
    __shared__ int s[256];
    int i = blockIdx.x * 256 + threadIdx.x;
    s[threadIdx.x] = (i < n) ? in[i] : 0;
    __syncthreads();
    for (int off = 128; off > 0; off >>= 1) {
        if (threadIdx.x < off) s[threadIdx.x] += s[threadIdx.x + off];
        __syncthreads();
    }
    if (threadIdx.x == 0) part[blockIdx.x] = s[0];
}
__global__ void k_scan_single(int* __restrict__ a, int n) {
    __shared__ int s[256];
    int v = (threadIdx.x < n) ? a[threadIdx.x] : 0;
    s[threadIdx.x] = v; __syncthreads();
    for (int off = 1; off < 256; off <<= 1) {
        int t = (threadIdx.x >= off) ? s[threadIdx.x - off] : 0;
        __syncthreads(); s[threadIdx.x] += t; __syncthreads();
    }
    if (threadIdx.x < n) a[threadIdx.x] = s[threadIdx.x] - v;
}
__global__ void k_scan_add(int* __restrict__ a, int n, const int* __restrict__ off) {
    __shared__ int s[256];
    int i = blockIdx.x * 256 + threadIdx.x;
    int v = (i < n) ? a[i] : 0;
    s[threadIdx.x] = v; __syncthreads();
    for (int o = 1; o < 256; o <<= 1) {
        int t = (threadIdx.x >= o) ? s[threadIdx.x - o] : 0;
        __syncthreads(); s[threadIdx.x] += t; __syncthreads();
    }
    if (i < n) a[i] = s[threadIdx.x] - v + off[blockIdx.x];
}
__global__ void k_scan_out(const int* __restrict__ in, int n, const int* __restrict__ boff,
                           int* __restrict__ out) {
    __shared__ int s[256];
    int i = blockIdx.x * 256 + threadIdx.x;
    int v = (i < n) ? in[i] : 0;
    s[threadIdx.x] = v; __syncthreads();
    for (int o = 1; o < 256; o <<= 1) {
        int t = (threadIdx.x >= o) ? s[threadIdx.x - o] : 0;
        __syncthreads(); s[threadIdx.x] += t; __syncthreads();
    }
    if (i < n) out[i] = s[threadIdx.x] - v + boff[blockIdx.x];
    if (i == n - 1) out[n] = s[threadIdx.x] + boff[blockIdx.x];
}
__global__ void k_fill_lg(const int* __restrict__ lg, const int* __restrict__ rowptr,
                          int* __restrict__ cnt, int* __restrict__ srcidx) {
    int i = blockIdx.x * blockDim.x + threadIdx.x;
    if (i >= LEE) return;
    int d = lg[LEE + i];
    int pos = rowptr[d] + atomicAdd(&cnt[d], 1);
    srcidx[pos] = lg[i];
}
__global__ void k_fill_n(const int* __restrict__ ei, const int* __restrict__ rowptr,
                         int* __restrict__ cnt, int* __restrict__ nidx) {
    int i = blockIdx.x * blockDim.x + threadIdx.x;
    if (i >= EE) return;
    int d = ei[EE + i];
    int pos = rowptr[d] + atomicAdd(&cnt[d], 1);
    nidx[pos] = i;
}

// ---------- main kernels ----------

// xu = bf16(x @ W_u), xv = bf16(x @ W_v)
__global__ void k_node_mm(const float* __restrict__ x, const float* __restrict__ Wu,
                          const float* __restrict__ Wv, ushort_t* __restrict__ xu,
                          ushort_t* __restrict__ xv) {
    __shared__ float su[64 * 64];
    __shared__ float sv[64 * 64];
    int tid = threadIdx.x;
    for (int i = tid; i < 64 * 64; i += blockDim.x) { su[i] = Wu[i]; sv[i] = Wv[i]; }
    __syncthreads();
    int row = blockIdx.x * 4 + (tid >> 6);
    int f = tid & 63;
    if (row >= NN) return;
    const float* xr = x + (long long)row * 64;
    float au = 0.f, av = 0.f;
    #pragma unroll
    for (int k = 0; k < 64; ++k) {
        float xv_ = xr[k];
        au += xv_ * su[k * 64 + f];
        av += xv_ * sv[k * 64 + f];
    }
    xu[(long long)row * 64 + f] = f2b(au);
    xv[(long long)row * 64 + f] = f2b(av);
}

// eab[e][f] = bf16((xu[ei0] + xv[ei1] + eattr @ W_e)/3); 2 feats/lane, 2 edges/wave
__global__ void k_ea_b16(const ushort_t* __restrict__ xu, const ushort_t* __restrict__ xv,
                         const float* __restrict__ eattr, const float* __restrict__ We,
                         const int* __restrict__ ei, ushort_t* __restrict__ eab) {
    __shared__ float swe[16 * 64];
    int tid = threadIdx.x;
    for (int i = tid; i < 1024; i += 256) swe[i] = We[i];
    __syncthreads();
    int e = blockIdx.x * 8 + (tid >> 5);
    int f2 = (tid & 31) * 2;
    if (e >= EE) return;
    int s = ei[e];
    int d = ei[EE + e];
    unsigned us = *(const unsigned*)&xu[(long long)s * 64 + f2];
    unsigned ud = *(const unsigned*)&xv[(long long)d * 64 + f2];
    const float* ar = eattr + (long long)e * 16;
    float a0 = 0.f, a1 = 0.f;
    #pragma unroll
    for (int k = 0; k < 16; ++k) {
        float w = ar[k];
        a0 += w * swe[k * 64 + f2];
        a1 += w * swe[k * 64 + f2 + 1];
    }
    float v0 = (b2f((ushort_t)us) + b2f((ushort_t)ud) + a0) * (1.0f / 3.0f);
    float v1 = (b2f((ushort_t)(us >> 16)) + b2f((ushort_t)(ud >> 16)) + a1) * (1.0f / 3.0f);
    *(unsigned*)&eab[(long long)e * 64 + f2] = (unsigned)f2b(v0) | ((unsigned)f2b(v1) << 16);
}

// out[d] = eab[d] + sum_{src} prev[src]; xw[d] = out[d].gatW. 2 feats/lane, 2 edges/wave
__global__ void k_mp_gather(const ushort_t* __restrict__ prev,
                            const ushort_t* __restrict__ eab,
                            const int* __restrict__ rowptr, const int* __restrict__ srcidx,
                            const float* __restrict__ gatW,
                            ushort_t* __restrict__ outb, float* __restrict__ xw) {
    int tid = threadIdx.x;
    int d = blockIdx.x * 8 + (tid >> 5);
    int f2 = (tid & 31) * 2;
    if (d >= EE) return;
    unsigned ue = *(const unsigned*)&eab[(long long)d * 64 + f2];
    float a0 = b2f((ushort_t)ue), a1 = b2f((ushort_t)(ue >> 16));
    int p0 = rowptr[d], p1 = rowptr[d + 1];
    int j = p0;
    for (; j + 4 <= p1; j += 4) {
        int s0 = srcidx[j], s1 = srcidx[j + 1], s2 = srcidx[j + 2], s3 = srcidx[j + 3];
        unsigned u0 = *(const unsigned*)&prev[(long long)s0 * 64 + f2];
        unsigned u1 = *(const unsigned*)&prev[(long long)s1 * 64 + f2];
        unsigned u2 = *(const unsigned*)&prev[(long long)s2 * 64 + f2];
        unsigned u3 = *(const unsigned*)&prev[(long long)s3 * 64 + f2];
        a0 += (b2f((ushort_t)u0) + b2f((ushort_t)u1)) + (b2f((ushort_t)u2) + b2f((ushort_t)u3));
        a1 += (b2f((ushort_t)(u0 >> 16)) + b2f((ushort_t)(u1 >> 16))) +
              (b2f((ushort_t)(u2 >> 16)) + b2f((ushort_t)(u3 >> 16)));
    }
    for (; j < p1; ++j) {
        unsigned u0 = *(const unsigned*)&prev[(long long)srcidx[j] * 64 + f2];
        a0 += b2f((ushort_t)u0);
        a1 += b2f((ushort_t)(u0 >> 16));
    }
    *(unsigned*)&outb[(long long)d * 64 + f2] = (unsigned)f2b(a0) | ((unsigned)f2b(a1) << 16);
    float w = a0 * gatW[f2] + a1 * gatW[f2 + 1];
    #pragma unroll
    for (int o = 16; o > 0; o >>= 1) w += __shfl_down(w, o, 32);
    if ((tid & 31) == 0) xw[d] = w;
}

// fused GAT: per dst edge, serial max / exp-sum / weighted-sum over CSR in-edges + self-loop
__global__ void k_gat_fused(const float* __restrict__ xw,
                            const int* __restrict__ rowptr, const int* __restrict__ srcidx,
                            const float* __restrict__ att_s, const float* __restrict__ att_d,
                            const float* __restrict__ gbias, float* __restrict__ xc) {
    int e = blockIdx.x * blockDim.x + threadIdx.x;
    if (e >= EE) return;
    float as = att_s[0], ad = att_d[0];
    float xwd = xw[e];
    float adt = xwd * ad;
    float aself = xwd * as + adt;
    if (aself < 0.f) aself *= 0.2f;
    int p0 = rowptr[e], p1 = rowptr[e + 1];
    float m = aself;
    for (int j = p0; j < p1; ++j) {
        float a = xw[srcidx[j]] * as + adt;
        if (a < 0.f) a *= 0.2f;
        m = fmaxf(m, a);
    }
    float ssum = expf(aself - m);
    float wsum = ssum * xwd;
    for (int j = p0; j < p1; ++j) {
        float xs = xw[srcidx[j]];
        float a = xs * as + adt;
        if (a < 0.f) a *= 0.2f;
        float ev = expf(a - m);
        ssum += ev;
        wsum += ev * xs;
    }
    xc[e] = wsum / (ssum + 1e-16f) + gbias[0];
}

__global__ void k_batchptr(const int* __restrict__ batch, int* __restrict__ bptr) {
    int e = blockIdx.x * blockDim.x + threadIdx.x;
    if (e >= EE) return;
    int b = batch[e];
    int bp = (e == 0) ? -1 : batch[e - 1];
    for (int q = bp + 1; q <= b; ++q) bptr[q] = e;
    if (e == EE - 1)
        for (int q = b + 1; q <= BBATCH; ++q) bptr[q] = EE;
}

// per-batch: softmax(xc) over segment, weighted-sum pool of bf16 out
__global__ void k_pool(const float* __restrict__ xc, const ushort_t* __restrict__ out,
                       const int* __restrict__ bptr, float* __restrict__ gout) {
    int b = blockIdx.x;
    int p0 = bptr[b], p1 = bptr[b + 1];
    __shared__ float red[256];
    int tid = threadIdx.x;
    float mx = -INFINITY;
    for (int e = p0 + tid; e < p1; e += 256) mx = fmaxf(mx, xc[e]);
    red[tid] = mx; __syncthreads();
    for (int s = 128; s > 0; s >>= 1) { if (tid < s) red[tid] = fmaxf(red[tid], red[tid + s]); __syncthreads(); }
    float m = red[0]; __syncthreads();
    float sm = 0.f;
    for (int e = p0 + tid; e < p1; e += 256) sm += expf(xc[e] - m);
    red[tid] = sm; __syncthreads();
    for (int s = 128; s > 0; s >>= 1) { if (tid < s) red[tid] += red[tid + s]; __syncthreads(); }
    float ssum = red[0] + 1e-16f; __syncthreads();
    int f = tid & 63, chunk = tid >> 6;
    float acc = 0.f;
    for (int e = p0 + chunk; e < p1; e += 4) {
        float w = expf(xc[e] - m);
        acc += w * b2f(out[(long long)e * 64 + f]);
    }
    red[tid] = acc; __syncthreads();
    if (chunk == 0) {
        float tot = red[f] + red[64 + f] + red[128 + f] + red[192 + f];
        gout[b * 64 + f] = tot / ssum;
    }
}

__global__ void k_gout_mm(const float* __restrict__ gout, const float* __restrict__ Wg,
                          const float* __restrict__ bg, float* __restrict__ gt) {
    __shared__ float sw[64 * 64];
    int tid = threadIdx.x;
    for (int i = tid; i < 4096; i += blockDim.x) sw[i] = Wg[i];
    __syncthreads();
    int row = blockIdx.x * 4 + (tid >> 6);
    int f = tid & 63;
    if (row >= BBATCH) return;
    const float* gr = gout + row * 64;
    float acc = bg[f];
    #pragma unroll
    for (int k = 0; k < 64; ++k) acc += gr[k] * sw[k * 64 + f];
    gt[row * 64 + f] = tanhf(acc);
}

__global__ void k_att(const float* __restrict__ g0, const float* __restrict__ g1,
                      const float* __restrict__ g2, const float* __restrict__ a,
                      const float* __restrict__ abias, float* __restrict__ sc) {
    int b = blockIdx.x;
    int f = threadIdx.x; // 64 threads
    float v0 = g0[b * 64 + f] * a[f * 3 + 0];
    float v1 = g1[b * 64 + f] * a[f * 3 + 1];
    float v2 = g2[b * 64 + f] * a[f * 3 + 2];
    #pragma unroll
    for (int o = 32; o > 0; o >>= 1) {
        v0 += __shfl_down(v0, o, 64);
        v1 += __shfl_down(v1, o, 64);
        v2 += __shfl_down(v2, o, 64);
    }
    if (f == 0) {
        float s0 = v0 + abias[0], s1 = v1 + abias[1], s2 = v2 + abias[2];
        float m = fmaxf(s0, fmaxf(s1, s2));
        float e0 = expf(s0 - m), e1 = expf(s1 - m), e2 = expf(s2 - m);
        float inv = 1.0f / (e0 + e1 + e2);
        sc[b * 3 + 0] = e0 * inv; sc[b * 3 + 1] = e1 * inv; sc[b * 3 + 2] = e2 * inv;
    }
}

// o1 <- sum_t o_t * sc_t[batch]   (elementwise, in place on o1)
__global__ void k_comb(ushort_t* __restrict__ o1, const ushort_t* __restrict__ o2,
                       const ushort_t* __restrict__ o3, const float* __restrict__ sc,
                       const int* __restrict__ batch) {
    long long idx = (long long)blockIdx.x * blockDim.x + threadIdx.x;
    if (idx >= (long long)EE * 64) return;
    int e = (int)(idx >> 6);
    int b = batch[e];
    float v = b2f(o1[idx]) * sc[b * 3] + b2f(o2[idx]) * sc[b * 3 + 1] + b2f(o3[idx]) * sc[b * 3 + 2];
    o1[idx] = f2b(v);
}

// xnb[n] = bf16(x[n] + sum over in-edges of comb[e])
__global__ void k_node_gather(const ushort_t* __restrict__ comb, const int* __restrict__ nrow,
                              const int* __restrict__ nidx, const float* __restrict__ x,
                              ushort_t* __restrict__ xnb) {
    int tid = threadIdx.x;
    int n = blockIdx.x * 4 + (tid >> 6);
    int f = tid & 63;
    if (n >= NN) return;
    float acc = x[(long long)n * 64 + f];
    int p0 = nrow[n], p1 = nrow[n + 1];
    int j = p0;
    for (; j + 4 <= p1; j += 4) {
        int e0 = nidx[j], e1 = nidx[j + 1], e2 = nidx[j + 2], e3 = nidx[j + 3];
        float v0 = b2f(comb[(long long)e0 * 64 + f]);
        float v1 = b2f(comb[(long long)e1 * 64 + f]);
        float v2 = b2f(comb[(long long)e2 * 64 + f]);
        float v3 = b2f(comb[(long long)e3 * 64 + f]);
        acc += (v0 + v1) + (v2 + v3);
    }
    for (; j < p1; ++j) acc += b2f(comb[(long long)nidx[j] * 64 + f]);
    xnb[(long long)n * 64 + f] = f2b(acc);
}

// column stats of a bf16 matrix (blockDim.x == ncols)
__global__ void k_colstats_b16(const ushort_t* __restrict__ X, int ncols, int nrows,
                               float* __restrict__ csum, float* __restrict__ csumsq) {
    int c = threadIdx.x;
    int rpb = CDIV(nrows, (int)gridDim.x);
    int r0 = blockIdx.x * rpb;
    int r1 = min(r0 + rpb, nrows);
    float s = 0.f, s2 = 0.f;
    for (int r = r0; r < r1; ++r) {
        float v = b2f(X[(long long)r * ncols + c]);
        s += v; s2 += v * v;
    }
    atomicAdd(&csum[c], s);
    atomicAdd(&csumsq[c], s2);
}

// LDS-tiled transpose+convert: W [K,M] f32 -> Wt [M,K] bf16
__global__ void k_wtrans(const float* __restrict__ W, int K, int M, ushort_t* __restrict__ Wt) {
    __shared__ ushort_t tile[32][33];
    int kb = blockIdx.y * 32, mb = blockIdx.x * 32;
    int tx = threadIdx.x & 31, ty = threadIdx.x >> 5;   // 256 threads: ty 0..7
    for (int dy = ty; dy < 32; dy += 8) {
        int k = kb + dy, m = mb + tx;
        tile[dy][tx] = (k < K && m < M) ? f2b(W[(long long)k * M + m]) : (ushort_t)0;
    }
    __syncthreads();
    for (int dy = ty; dy < 32; dy += 8) {
        int m = mb + dy, k = kb + tx;
        if (m < M && k < K) Wt[(long long)m * K + k] = tile[tx][dy];
    }
}

// LinBlock GEMM, full-M block: C = scale*(act(bn(A)) @ W + bias + res)
// A bf16 [nrows,KK] staged via LDS (BN+PReLU fused, converted ONCE per element);
// Wt bf16 [MT,KK] read direct from global (L2-resident). Block tile RT x MT,
// 8 waves in WR x WC grid; wave tile (RT/WR) x (MT/WC) via 16x16x32 frags.
// Output column stats fused (wave-reduced atomics).
template<int KK, int MT, int WR, int WC, int RT>
__global__ __launch_bounds__(512) void k_gemm_fused(
    const ushort_t* __restrict__ A, const ushort_t* __restrict__ Wt,
    const float* __restrict__ bias, const ushort_t* __restrict__ resb,
    const float* __restrict__ csum, const float* __restrict__ csumsq,
    const float* __restrict__ g, const float* __restrict__ bb,
    const float* __restrict__ pr, float scale, int nrows,
    ushort_t* __restrict__ Cb, float* __restrict__ Cf,
    float* __restrict__ osum, float* __restrict__ osumsq) {
    constexpr int RTW = RT / WR;      // rows per wave
    constexpr int MTW = MT / WC;      // cols per wave
    constexpr int FM = RTW / 16;
    constexpr int FN = MTW / 16;
    __shared__ ushort_t sA[RT][36];   // 72B row stride: b64 reads spread banks
    __shared__ float sScl[KK], sOff[KK];
    int tid = threadIdx.x;
    int wave = tid >> 6, lane = tid & 63;
    int l16 = lane & 15, klo = lane >> 4;
    int wrow = wave / WC, wcol = wave % WC;
    long long rowBase = (long long)blockIdx.x * RT;
    float prs = pr ? pr[0] : 1.0f;
    const float invn = 1.0f / (float)NN;
    for (int c = tid; c < KK; c += 512) {
        float mean = csum[c] * invn;
        float var = csumsq[c] * invn - mean * mean;
        float scl = rsqrtf(var + 1e-5f) * g[c];
        sScl[c] = scl;
        sOff[c] = bb[c] - mean * scl;
    }
    __syncthreads();
    f32x4 acc[FM][FN] = {};
    for (int k0 = 0; k0 < KK; k0 += 32) {
        // stage A: RT rows x 32 k, 8 elems (16B) per thread per iter, BN+act fused
        #pragma unroll
        for (int it = 0; it < RT * 32 / (512 * 8); ++it) {
            int idx = (it * 512 + tid) * 8;
            int r = idx >> 5, kk = idx & 31;
            long long gr = rowBase + r;
            uint4 raw = {0u, 0u, 0u, 0u};
            if (gr < nrows) raw = *(const uint4*)&A[gr * KK + k0 + kk];
            unsigned outw[4];
            #pragma unroll
            for (int q = 0; q < 4; ++q) {
                unsigned rw = ((const unsigned*)&raw)[q];
                int c = k0 + kk + q * 2;
                float t0 = b2f((ushort_t)rw) * sScl[c] + sOff[c];
                float t1 = b2f((ushort_t)(rw >> 16)) * sScl[c + 1] + sOff[c + 1];
                if (t0 < 0.f) t0 *= prs;
                if (t1 < 0.f) t1 *= prs;
                outw[q] = (unsigned)f2b(t0) | ((unsigned)f2b(t1) << 16);
            }
            uint2 w0; w0.x = outw[0]; w0.y = outw[1];
            uint2 w1; w1.x = outw[2]; w1.y = outw[3];
            *(uint2*)&sA[r][kk] = w0;
            *(uint2*)&sA[r][kk + 4] = w1;
        }
        __syncthreads();
        // B frags direct from global Wt[col][k] (L2-resident)
        bf16x8 bfr[FN];
        #pragma unroll
        for (int n = 0; n < FN; ++n) {
            int col = wcol * MTW + n * 16 + l16;
            bfr[n] = *(const bf16x8*)&Wt[(long long)col * KK + k0 + klo * 8];
        }
        // A frags from LDS (2 x b64 each)
        bf16x8 afr[FM];
        #pragma unroll
        for (int m = 0; m < FM; ++m) {
            union { uint2 p[2]; bf16x8 v; } u;
            int row = wrow * RTW + m * 16 + l16;
            u.p[0] = *(const uint2*)&sA[row][klo * 8];
            u.p[1] = *(const uint2*)&sA[row][klo * 8 + 4];
            afr[m] = u.v;
        }
        #pragma unroll
        for (int m = 0; m < FM; ++m)
            #pragma unroll
            for (int n = 0; n < FN; ++n)
                acc[m][n] = __builtin_amdgcn_mfma_f32_16x16x32_bf16(afr[m], bfr[n], acc[m][n], 0, 0, 0);
        __syncthreads();
    }
    // epilogue: C/D col=lane&15, row=(lane>>4)*4+reg; fused bias/res/scale/stats
    #pragma unroll
    for (int m = 0; m < FM; ++m) {
        #pragma unroll
        for (int n = 0; n < FN; ++n) {
            int col = wcol * MTW + n * 16 + l16;
            long long row0 = rowBase + wrow * RTW + m * 16 + klo * 4;
            float bcol = bias[col];
            float s = 0.f, s2 = 0.f;
            #pragma unroll
            for (int r = 0; r < 4; ++r) {
                long long row = row0 + r;
                if (row < nrows) {
                    float v = acc[m][n][r] + bcol;
                    if (resb) v += b2f(resb[row * MT + col]);
                    v *= scale;
                    if (Cf) Cf[row * MT + col] = v;
                    if (Cb) Cb[row * MT + col] = f2b(v);
                    s += v; s2 += v * v;
                }
            }
            if (osum) {
                s += __shfl_down(s, 32, 64);
                s2 += __shfl_down(s2, 32, 64);
                s += __shfl_down(s, 16, 64);
                s2 += __shfl_down(s2, 16, 64);
                if (lane < 16) {
                    atomicAdd(&osum[col], s);
                    atomicAdd(&osumsq[col], s2);
                }
            }
        }
    }
}

extern "C" void kernel_launch(void* const* d_in, const int* in_sizes, int n_in,
                              void* d_out, int out_size, void* d_ws, size_t ws_size,
                              hipStream_t stream) {
    const float* x       = (const float*)d_in[0];
    const float* eattr   = (const float*)d_in[1];
    const int*   ei      = (const int*)d_in[2];
    const int*   lg      = (const int*)d_in[3];
    const int*   batch   = (const int*)d_in[4];
    const float* W_u     = (const float*)d_in[5];
    const float* W_v     = (const float*)d_in[6];
    const float* W_e     = (const float*)d_in[7];
    const float* gat_W   = (const float*)d_in[8];
    const float* att_s   = (const float*)d_in[9];
    const float* att_d   = (const float*)d_in[10];
    const float* gat_b   = (const float*)d_in[11];
    const float* a_att   = (const float*)d_in[12];
    const float* a_bias  = (const float*)d_in[13];
    const float* W_gout  = (const float*)d_in[14];
    const float* b_gout  = (const float*)d_in[15];
    const float* bn1_g   = (const float*)d_in[16];
    const float* bn1_b   = (const float*)d_in[17];
    const float* lb_W1   = (const float*)d_in[18];
    const float* lb_b1   = (const float*)d_in[19];
    const float* lb_bn_g = (const float*)d_in[20];
    const float* lb_bn_b = (const float*)d_in[21];
    const float* lb_pr   = (const float*)d_in[22];
    const float* lb_W    = (const float*)d_in[23];
    const float* lb_b    = (const float*)d_in[24];
    const float* bn5_g   = (const float*)d_in[25];
    const float* bn5_b   = (const float*)d_in[26];
    const float* pr5     = (const float*)d_in[27];
    const float* lb_W5   = (const float*)d_in[28];
    const float* lb_b5   = (const float*)d_in[29];
    float* out_final = (float*)d_out;

    // ---------------- workspace layout (~186 MB) ----------------
    const long long ESZ = (long long)EE * FF;
    const long long NSZ = (long long)NN * FF;
    char* cur = (char*)d_ws;
    auto alloc = [&](size_t bytes) -> void* {
        void* p = (void*)cur;
        cur += (bytes + 255) & ~(size_t)255;
        return p;
    };
    ushort_t* XU = (ushort_t*)alloc(NSZ * 2);
    ushort_t* XV = (ushort_t*)alloc(NSZ * 2);
    ushort_t* O1 = (ushort_t*)alloc(ESZ * 2);
    ushort_t* O2 = (ushort_t*)alloc(ESZ * 2);
    ushort_t* O3 = (ushort_t*)alloc(ESZ * 2);   // holds EAB until iter-3 overwrites it
    float* XW = (float*)alloc((size_t)EE * 4);
    float* XC = (float*)alloc((size_t)EE * 4);
    ushort_t* XNB = (ushort_t*)alloc(NSZ * 2);
    float* GRAW = (float*)alloc(BBATCH * FF * 4);
    float* G0 = (float*)alloc(BBATCH * FF * 4);
    float* G1 = (float*)alloc(BBATCH * FF * 4);
    float* G2 = (float*)alloc(BBATCH * FF * 4);
    float* SCATT = (float*)alloc(BBATCH * 3 * 4);
    int* BPTR = (int*)alloc((BBATCH + 1) * 4);
    int* LROW = (int*)alloc((size_t)(EE + 1) * 4);
    int* LSRC = (int*)alloc((size_t)LEE * 4);
    int* LCNT = (int*)alloc((size_t)EE * 4);
    int* NROW = (int*)alloc((size_t)(NN + 1) * 4);
    int* NIDX = (int*)alloc((size_t)EE * 4);
    int* NCNT = (int*)alloc((size_t)NN * 4);
    int* SP0 = (int*)alloc(2048 * 4);
    int* SP1 = (int*)alloc(256 * 4);
    float* STATS = (float*)alloc(5 * 2 * SFD * 4);   // 5 stages x (sum, sumsq)[384]
    ushort_t* WT1 = (ushort_t*)alloc((size_t)SFD * FF * 2);       // [384][64]
    ushort_t* WT2 = (ushort_t*)alloc((size_t)SFD * SFD * 2);      // [384][384]
    ushort_t* WT3 = (ushort_t*)alloc((size_t)SFD * SFD * 2);
    ushort_t* WT4 = (ushort_t*)alloc((size_t)SFD * SFD * 2);
    ushort_t* WT5 = (ushort_t*)alloc((size_t)FF * SFD * 2);       // [64][384]
    if ((size_t)(cur - (char*)d_ws) > ws_size) return;  // diagnostic: zeros -> ws too small

    // LinBlock bf16 activations alias the O region (dead by then): 4 x 38.4 MB = 153.6 MB
    ushort_t* T1B = O1;
    ushort_t* T2B = T1B + (long long)NN * SFD;
    ushort_t* T3B = T2B + (long long)NN * SFD;
    ushort_t* T4B = T3B + (long long)NN * SFD;
    float* CS[5][2];
    for (int i = 0; i < 5; ++i) { CS[i][0] = STATS + i * 2 * SFD; CS[i][1] = CS[i][0] + SFD; }
    float* GTS[3] = {G0, G1, G2};

    hipMemsetAsync(STATS, 0, 5 * 2 * SFD * 4, stream);

    // 0. weight transpose+convert (bf16 [col][k]), once per launch
    {
        dim3 gt(SFD / 32, FF / 32);
        k_wtrans<<<gt, 256, 0, stream>>>(lb_W1, FF, SFD, WT1);
        dim3 gs(SFD / 32, SFD / 32);
        k_wtrans<<<gs, 256, 0, stream>>>(lb_W, SFD, SFD, WT2);
        k_wtrans<<<gs, 256, 0, stream>>>(lb_W + (long long)SFD * SFD, SFD, SFD, WT3);
        k_wtrans<<<gs, 256, 0, stream>>>(lb_W + 2LL * SFD * SFD, SFD, SFD, WT4);
        dim3 g5(FF / 32, SFD / 32);
        k_wtrans<<<g5, 256, 0, stream>>>(lb_W5, SFD, FF, WT5);
    }

    // 1. node transforms + batch rowptr
    k_node_mm<<<CDIV(NN, 4), 256, 0, stream>>>(x, W_u, W_v, XU, XV);
    k_batchptr<<<CDIV(EE, 256), 256, 0, stream>>>(batch, BPTR);

    // 2. build line-graph CSR (by dst)
    {
        hipMemsetAsync(LCNT, 0, (size_t)EE * 4, stream);
        k_hist<<<CDIV(LEE, 256), 256, 0, stream>>>(lg + LEE, LEE, LCNT);
        int nb0 = CDIV(EE, 256), nb1 = CDIV(nb0, 256);
        k_part<<<nb0, 256, 0, stream>>>(LCNT, EE, SP0);
        k_part<<<nb1, 256, 0, stream>>>(SP0, nb0, SP1);
        k_scan_single<<<1, 256, 0, stream>>>(SP1, nb1);
        k_scan_add<<<nb1, 256, 0, stream>>>(SP0, nb0, SP1);
        k_scan_out<<<nb0, 256, 0, stream>>>(LCNT, EE, SP0, LROW);
        hipMemsetAsync(LCNT, 0, (size_t)EE * 4, stream);
        k_fill_lg<<<CDIV(LEE, 256), 256, 0, stream>>>(lg, LROW, LCNT, LSRC);
    }
    // 3. build node CSR (by ei1)
    {
        hipMemsetAsync(NCNT, 0, (size_t)NN * 4, stream);
        k_hist<<<CDIV(EE, 256), 256, 0, stream>>>(ei + EE, EE, NCNT);
        int nb0 = CDIV(NN, 256), nb1 = CDIV(nb0, 256);
        k_part<<<nb0, 256, 0, stream>>>(NCNT, NN, SP0);
        k_part<<<nb1, 256, 0, stream>>>(SP0, nb0, SP1);
        k_scan_single<<<1, 256, 0, stream>>>(SP1, nb1);
        k_scan_add<<<nb1, 256, 0, stream>>>(SP0, nb0, SP1);
        k_scan_out<<<nb0, 256, 0, stream>>>(NCNT, NN, SP0, NROW);
        hipMemsetAsync(NCNT, 0, (size_t)NN * 4, stream);
        k_fill_n<<<CDIV(EE, 256), 256, 0, stream>>>(ei, NROW, NCNT, NIDX);
    }

    const int EB8 = CDIV(EE, 8);

    auto gat_pool = [&](ushort_t* buf, int t) {
        k_gat_fused<<<CDIV(EE, 256), 256, 0, stream>>>(XW, LROW, LSRC, att_s, att_d, gat_b, XC);
        k_pool<<<BBATCH, 256, 0, stream>>>(XC, buf, BPTR, GRAW);
        k_gout_mm<<<CDIV(BBATCH, 4), 256, 0, stream>>>(GRAW, W_gout, b_gout, GTS[t]);
    };

    // 4. EAB + message-passing iterations (uniform gathers, bf16 storage)
    k_ea_b16<<<EB8, 256, 0, stream>>>(XU, XV, eattr, W_e, ei, O3);              // O3 = EAB
    k_mp_gather<<<EB8, 256, 0, stream>>>(O3, O3, LROW, LSRC, gat_W, O1, XW);    // O1 = out1
    gat_pool(O1, 0);
    k_mp_gather<<<EB8, 256, 0, stream>>>(O1, O3, LROW, LSRC, gat_W, O2, XW);    // O2 = out2
    gat_pool(O2, 1);
    k_mp_gather<<<EB8, 256, 0, stream>>>(O2, O3, LROW, LSRC, gat_W, O3, XW);    // O3 = out3
    gat_pool(O3, 2);

    // 5. iteration attention + combine + node aggregation (writes bf16 XNB)
    k_att<<<BBATCH, 64, 0, stream>>>(G0, G1, G2, a_att, a_bias, SCATT);
    k_comb<<<(int)CDIV(ESZ, 256), 256, 0, stream>>>(O1, O2, O3, SCATT, batch);
    k_node_gather<<<CDIV(NN, 4), 256, 0, stream>>>(O1, NROW, NIDX, x, XNB);
    k_colstats_b16<<<256, FF, 0, stream>>>(XNB, FF, NN, CS[0][0], CS[0][1]);

    // 6. LinBlock: full-M MFMA GEMMs, BN fused, stats fused into epilogues
    {
        const int GB128 = CDIV(NN, 128);   // 391
        // lin1: x1 = bn1(xn) @ W1 + b1    (K=64, no prelu)
        k_gemm_fused<64, 384, 2, 4, 128><<<GB128, 512, 0, stream>>>(XNB, WT1, lb_b1, nullptr,
            CS[0][0], CS[0][1], bn1_g, bn1_b, nullptr, 1.0f, NN,
            T1B, nullptr, CS[1][0], CS[1][1]);
        // lin2: h1 = prelu(bn(x1)) @ W[0] + b[0]
        k_gemm_fused<384, 384, 2, 4, 128><<<GB128, 512, 0, stream>>>(T1B, WT2, lb_b, nullptr,
            CS[1][0], CS[1][1], lb_bn_g, lb_bn_b, lb_pr, 1.0f, NN,
            T2B, nullptr, CS[2][0], CS[2][1]);
        // lin3: x2 = (prelu(bn(h1)) @ W[1] + b[1] + x1) / 2
        k_gemm_fused<384, 384, 2, 4, 128><<<GB128, 512, 0, stream>>>(T2B, WT3, lb_b + SFD, T1B,
            CS[2][0], CS[2][1], lb_bn_g + SFD, lb_bn_b + SFD, lb_pr + 1, 0.5f, NN,
            T3B, nullptr, CS[3][0], CS[3][1]);
        // lin4: x3 = (prelu(bn(x2)) @ W[2] + b[2] + x2) / 2
        k_gemm_fused<384, 384, 2, 4, 128><<<GB128, 512, 0, stream>>>(T3B, WT4, lb_b + 2 * SFD, T3B,
            CS[3][0], CS[3][1], lb_bn_g + 2 * SFD, lb_bn_b + 2 * SFD, lb_pr + 2, 0.5f, NN,
            T4B, nullptr, CS[4][0], CS[4][1]);
        // lin5: out = prelu(bn5(x3)) @ W5 + b5    (f32 out, 256x64 tile)
        k_gemm_fused<384, 64, 8, 1, 256><<<CDIV(NN, 256), 512, 0, stream>>>(T4B, WT5, lb_b5, nullptr,
            CS[4][0], CS[4][1], bn5_g, bn5_b, pr5, 1.0f, NN,
            nullptr, out_final, nullptr, nullptr);
    }
}

// Round 9
// 1793.099 us; speedup vs baseline: 1.2293x; 1.1144x over previous
//
#include <hip/hip_runtime.h>
#include <math.h>

#define NN 50000
#define EE 400000
#define LEE 1600000
#define BBATCH 256
#define FF 64
#define EDD 16
#define NITER 3
#define SFD 384

#define CDIV(a,b) (((a)+(b)-1)/(b))

typedef unsigned short ushort_t;
typedef __attribute__((ext_vector_type(8))) short bf16x8;
typedef __attribute__((ext_vector_type(4))) float f32x4;

// ---------- helpers ----------
__device__ inline float b2f(ushort_t u) { return __uint_as_float(((unsigned)u) << 16); }
__device__ inline ushort_t f2b(float f) {   // RNE
    unsigned u = __float_as_uint(f);
    return (ushort_t)((u + 0x7fffu + ((u >> 16) & 1u)) >> 16);
}

// ---------- small CSR-build kernels ----------
__global__ void k_hist(const int* __restrict__ idx, int n, int* __restrict__ cnt) {
    int i = blockIdx.x * blockDim.x + threadIdx.x;
    if (i < n) atomicAdd(&cnt[idx[i]], 1);
}
__global__ void k_part(const int* __restrict__ in, int n, int* __restrict__ part) {
    __shared__ int s[256];
    int i = blockIdx.x * 256 + threadIdx.x;
    s[threadIdx.x] = (i < n) ? in[i] : 0;
    __syncthreads();
    for (int off = 128; off > 0; off >>= 1) {
        if (threadIdx.x < off) s[threadIdx.x] += s[threadIdx.x + off];
        __syncthreads();
    }
    if (threadIdx.x == 0) part[blockIdx.x] = s[0];
}
__global__ void k_scan_single(int* __restrict__ a, int n) {
    __shared__ int s[256];
    int v = (threadIdx.x < n) ? a[threadIdx.x] : 0;
    s[threadIdx.x] = v; __syncthreads();
    for (int off = 1; off < 256; off <<= 1) {
        int t = (threadIdx.x >= off) ? s[threadIdx.x - off] : 0;
        __syncthreads(); s[threadIdx.x] += t; __syncthreads();
    }
    if (threadIdx.x < n) a[threadIdx.x] = s[threadIdx.x] - v;
}
__global__ void k_scan_add(int* __restrict__ a, int n, const int* __restrict__ off) {
    __shared__ int s[256];
    int i = blockIdx.x * 256 + threadIdx.x;
    int v = (i < n) ? a[i] : 0;
    s[threadIdx.x] = v; __syncthreads();
    for (int o = 1; o < 256; o <<= 1) {
        int t = (threadIdx.x >= o) ? s[threadIdx.x - o] : 0;
        __syncthreads(); s[threadIdx.x] += t; __syncthreads();
    }
    if (i < n) a[i] = s[threadIdx.x] - v + off[blockIdx.x];
}
__global__ void k_scan_out(const int* __restrict__ in, int n, const int* __restrict__ boff,
                           int* __restrict__ out) {
    __shared__ int s[256];
    int i = blockIdx.x * 256 + threadIdx.x;
    int v = (i < n) ? in[i] : 0;
    s[threadIdx.x] = v; __syncthreads();
    for (int o = 1; o < 256; o <<= 1) {
        int t = (threadIdx.x >= o) ? s[threadIdx.x - o] : 0;
        __syncthreads(); s[threadIdx.x] += t; __syncthreads();
    }
    if (i < n) out[i] = s[threadIdx.x] - v + boff[blockIdx.x];
    if (i == n - 1) out[n] = s[threadIdx.x] + boff[blockIdx.x];
}
__global__ void k_fill_lg(const int* __restrict__ lg, const int* __restrict__ rowptr,
                          int* __restrict__ cnt, int* __restrict__ srcidx) {
    int i = blockIdx.x * blockDim.x + threadIdx.x;
    if (i >= LEE) return;
    int d = lg[LEE + i];
    int pos = rowptr[d] + atomicAdd(&cnt[d], 1);
    srcidx[pos] = lg[i];
}
__global__ void k_fill_n(const int* __restrict__ ei, const int* __restrict__ rowptr,
                         int* __restrict__ cnt, int* __restrict__ nidx) {
    int i = blockIdx.x * blockDim.x + threadIdx.x;
    if (i >= EE) return;
    int d = ei[EE + i];
    int pos = rowptr[d] + atomicAdd(&cnt[d], 1);
    nidx[pos] = i;
}

// ---------- main kernels ----------

// xu = bf16(x @ W_u), xv = bf16(x @ W_v)
__global__ void k_node_mm(const float* __restrict__ x, const float* __restrict__ Wu,
                          const float* __restrict__ Wv, ushort_t* __restrict__ xu,
                          ushort_t* __restrict__ xv) {
    __shared__ float su[64 * 64];
    __shared__ float sv[64 * 64];
    int tid = threadIdx.x;
    for (int i = tid; i < 64 * 64; i += blockDim.x) { su[i] = Wu[i]; sv[i] = Wv[i]; }
    __syncthreads();
    int row = blockIdx.x * 4 + (tid >> 6);
    int f = tid & 63;
    if (row >= NN) return;
    const float* xr = x + (long long)row * 64;
    float au = 0.f, av = 0.f;
    #pragma unroll
    for (int k = 0; k < 64; ++k) {
        float xv_ = xr[k];
        au += xv_ * su[k * 64 + f];
        av += xv_ * sv[k * 64 + f];
    }
    xu[(long long)row * 64 + f] = f2b(au);
    xv[(long long)row * 64 + f] = f2b(av);
}

// eab[e][f] = bf16((xu[ei0] + xv[ei1] + eattr @ W_e)/3); 2 feats/lane, 2 edges/wave
__global__ void k_ea_b16(const ushort_t* __restrict__ xu, const ushort_t* __restrict__ xv,
                         const float* __restrict__ eattr, const float* __restrict__ We,
                         const int* __restrict__ ei, ushort_t* __restrict__ eab) {
    __shared__ float swe[16 * 64];
    int tid = threadIdx.x;
    for (int i = tid; i < 1024; i += 256) swe[i] = We[i];
    __syncthreads();
    int e = blockIdx.x * 8 + (tid >> 5);
    int f2 = (tid & 31) * 2;
    if (e >= EE) return;
    int s = ei[e];
    int d = ei[EE + e];
    unsigned us = *(const unsigned*)&xu[(long long)s * 64 + f2];
    unsigned ud = *(const unsigned*)&xv[(long long)d * 64 + f2];
    const float* ar = eattr + (long long)e * 16;
    float a0 = 0.f, a1 = 0.f;
    #pragma unroll
    for (int k = 0; k < 16; ++k) {
        float w = ar[k];
        a0 += w * swe[k * 64 + f2];
        a1 += w * swe[k * 64 + f2 + 1];
    }
    float v0 = (b2f((ushort_t)us) + b2f((ushort_t)ud) + a0) * (1.0f / 3.0f);
    float v1 = (b2f((ushort_t)(us >> 16)) + b2f((ushort_t)(ud >> 16)) + a1) * (1.0f / 3.0f);
    *(unsigned*)&eab[(long long)e * 64 + f2] = (unsigned)f2b(v0) | ((unsigned)f2b(v1) << 16);
}

// out[d] = eab[d] + sum_{src} prev[src]; xw[d] = out[d].gatW. 2 feats/lane, 2 edges/wave
__global__ void k_mp_gather(const ushort_t* __restrict__ prev,
                            const ushort_t* __restrict__ eab,
                            const int* __restrict__ rowptr, const int* __restrict__ srcidx,
                            const float* __restrict__ gatW,
                            ushort_t* __restrict__ outb, float* __restrict__ xw) {
    int tid = threadIdx.x;
    int d = blockIdx.x * 8 + (tid >> 5);
    int f2 = (tid & 31) * 2;
    if (d >= EE) return;
    unsigned ue = *(const unsigned*)&eab[(long long)d * 64 + f2];
    float a0 = b2f((ushort_t)ue), a1 = b2f((ushort_t)(ue >> 16));
    int p0 = rowptr[d], p1 = rowptr[d + 1];
    int j = p0;
    for (; j + 4 <= p1; j += 4) {
        int s0 = srcidx[j], s1 = srcidx[j + 1], s2 = srcidx[j + 2], s3 = srcidx[j + 3];
        unsigned u0 = *(const unsigned*)&prev[(long long)s0 * 64 + f2];
        unsigned u1 = *(const unsigned*)&prev[(long long)s1 * 64 + f2];
        unsigned u2 = *(const unsigned*)&prev[(long long)s2 * 64 + f2];
        unsigned u3 = *(const unsigned*)&prev[(long long)s3 * 64 + f2];
        a0 += (b2f((ushort_t)u0) + b2f((ushort_t)u1)) + (b2f((ushort_t)u2) + b2f((ushort_t)u3));
        a1 += (b2f((ushort_t)(u0 >> 16)) + b2f((ushort_t)(u1 >> 16))) +
              (b2f((ushort_t)(u2 >> 16)) + b2f((ushort_t)(u3 >> 16)));
    }
    for (; j < p1; ++j) {
        unsigned u0 = *(const unsigned*)&prev[(long long)srcidx[j] * 64 + f2];
        a0 += b2f((ushort_t)u0);
        a1 += b2f((ushort_t)(u0 >> 16));
    }
    *(unsigned*)&outb[(long long)d * 64 + f2] = (unsigned)f2b(a0) | ((unsigned)f2b(a1) << 16);
    float w = a0 * gatW[f2] + a1 * gatW[f2 + 1];
    #pragma unroll
    for (int o = 16; o > 0; o >>= 1) w += __shfl_down(w, o, 32);
    if ((tid & 31) == 0) xw[d] = w;
}

// fused GAT, one-pass online softmax over CSR in-edges + self-loop
__global__ void k_gat_fused(const float* __restrict__ xw,
                            const int* __restrict__ rowptr, const int* __restrict__ srcidx,
                            const float* __restrict__ att_s, const float* __restrict__ att_d,
                            const float* __restrict__ gbias, float* __restrict__ xc) {
    int e = blockIdx.x * blockDim.x + threadIdx.x;
    if (e >= EE) return;
    float as = att_s[0], ad = att_d[0];
    float xwd = xw[e];
    float adt = xwd * ad;
    float aself = xwd * as + adt;
    if (aself < 0.f) aself *= 0.2f;
    float m = aself;
    float ssum = 1.0f;          // exp(aself - m)
    float wsum = xwd;           // * xwd
    int p0 = rowptr[e], p1 = rowptr[e + 1];
    for (int j = p0; j < p1; ++j) {
        float xs = xw[srcidx[j]];
        float a = xs * as + adt;
        if (a < 0.f) a *= 0.2f;
        if (a > m) {
            float r = expf(m - a);
            ssum = ssum * r + 1.0f;
            wsum = wsum * r + xs;
            m = a;
        } else {
            float ev = expf(a - m);
            ssum += ev;
            wsum += ev * xs;
        }
    }
    xc[e] = wsum / (ssum + 1e-16f) + gbias[0];
}

__global__ void k_batchptr(const int* __restrict__ batch, int* __restrict__ bptr) {
    int e = blockIdx.x * blockDim.x + threadIdx.x;
    if (e >= EE) return;
    int b = batch[e];
    int bp = (e == 0) ? -1 : batch[e - 1];
    for (int q = bp + 1; q <= b; ++q) bptr[q] = e;
    if (e == EE - 1)
        for (int q = b + 1; q <= BBATCH; ++q) bptr[q] = EE;
}

// per-batch: softmax(xc) over segment, weighted-sum pool of bf16 out
__global__ void k_pool(const float* __restrict__ xc, const ushort_t* __restrict__ out,
                       const int* __restrict__ bptr, float* __restrict__ gout) {
    int b = blockIdx.x;
    int p0 = bptr[b], p1 = bptr[b + 1];
    __shared__ float red[256];
    int tid = threadIdx.x;
    float mx = -INFINITY;
    for (int e = p0 + tid; e < p1; e += 256) mx = fmaxf(mx, xc[e]);
    red[tid] = mx; __syncthreads();
    for (int s = 128; s > 0; s >>= 1) { if (tid < s) red[tid] = fmaxf(red[tid], red[tid + s]); __syncthreads(); }
    float m = red[0]; __syncthreads();
    float sm = 0.f;
    for (int e = p0 + tid; e < p1; e += 256) sm += expf(xc[e] - m);
    red[tid] = sm; __syncthreads();
    for (int s = 128; s > 0; s >>= 1) { if (tid < s) red[tid] += red[tid + s]; __syncthreads(); }
    float ssum = red[0] + 1e-16f; __syncthreads();
    int f = tid & 63, chunk = tid >> 6;
    float acc = 0.f;
    for (int e = p0 + chunk; e < p1; e += 4) {
        float w = expf(xc[e] - m);
        acc += w * b2f(out[(long long)e * 64 + f]);
    }
    red[tid] = acc; __syncthreads();
    if (chunk == 0) {
        float tot = red[f] + red[64 + f] + red[128 + f] + red[192 + f];
        gout[b * 64 + f] = tot / ssum;
    }
}

__global__ void k_gout_mm(const float* __restrict__ gout, const float* __restrict__ Wg,
                          const float* __restrict__ bg, float* __restrict__ gt) {
    __shared__ float sw[64 * 64];
    int tid = threadIdx.x;
    for (int i = tid; i < 4096; i += blockDim.x) sw[i] = Wg[i];
    __syncthreads();
    int row = blockIdx.x * 4 + (tid >> 6);
    int f = tid & 63;
    if (row >= BBATCH) return;
    const float* gr = gout + row * 64;
    float acc = bg[f];
    #pragma unroll
    for (int k = 0; k < 64; ++k) acc += gr[k] * sw[k * 64 + f];
    gt[row * 64 + f] = tanhf(acc);
}

__global__ void k_att(const float* __restrict__ g0, const float* __restrict__ g1,
                      const float* __restrict__ g2, const float* __restrict__ a,
                      const float* __restrict__ abias, float* __restrict__ sc) {
    int b = blockIdx.x;
    int f = threadIdx.x; // 64 threads
    float v0 = g0[b * 64 + f] * a[f * 3 + 0];
    float v1 = g1[b * 64 + f] * a[f * 3 + 1];
    float v2 = g2[b * 64 + f] * a[f * 3 + 2];
    #pragma unroll
    for (int o = 32; o > 0; o >>= 1) {
        v0 += __shfl_down(v0, o, 64);
        v1 += __shfl_down(v1, o, 64);
        v2 += __shfl_down(v2, o, 64);
    }
    if (f == 0) {
        float s0 = v0 + abias[0], s1 = v1 + abias[1], s2 = v2 + abias[2];
        float m = fmaxf(s0, fmaxf(s1, s2));
        float e0 = expf(s0 - m), e1 = expf(s1 - m), e2 = expf(s2 - m);
        float inv = 1.0f / (e0 + e1 + e2);
        sc[b * 3 + 0] = e0 * inv; sc[b * 3 + 1] = e1 * inv; sc[b * 3 + 2] = e2 * inv;
    }
}

// o1 <- sum_t o_t * sc_t[batch]   (elementwise, in place on o1)
__global__ void k_comb(ushort_t* __restrict__ o1, const ushort_t* __restrict__ o2,
                       const ushort_t* __restrict__ o3, const float* __restrict__ sc,
                       const int* __restrict__ batch) {
    long long idx = (long long)blockIdx.x * blockDim.x + threadIdx.x;
    if (idx >= (long long)EE * 64) return;
    int e = (int)(idx >> 6);
    int b = batch[e];
    float v = b2f(o1[idx]) * sc[b * 3] + b2f(o2[idx]) * sc[b * 3 + 1] + b2f(o3[idx]) * sc[b * 3 + 2];
    o1[idx] = f2b(v);
}

// xnb[n] = bf16(x[n] + sum over in-edges of comb[e])
__global__ void k_node_gather(const ushort_t* __restrict__ comb, const int* __restrict__ nrow,
                              const int* __restrict__ nidx, const float* __restrict__ x,
                              ushort_t* __restrict__ xnb) {
    int tid = threadIdx.x;
    int n = blockIdx.x * 4 + (tid >> 6);
    int f = tid & 63;
    if (n >= NN) return;
    float acc = x[(long long)n * 64 + f];
    int p0 = nrow[n], p1 = nrow[n + 1];
    int j = p0;
    for (; j + 4 <= p1; j += 4) {
        int e0 = nidx[j], e1 = nidx[j + 1], e2 = nidx[j + 2], e3 = nidx[j + 3];
        float v0 = b2f(comb[(long long)e0 * 64 + f]);
        float v1 = b2f(comb[(long long)e1 * 64 + f]);
        float v2 = b2f(comb[(long long)e2 * 64 + f]);
        float v3 = b2f(comb[(long long)e3 * 64 + f]);
        acc += (v0 + v1) + (v2 + v3);
    }
    for (; j < p1; ++j) acc += b2f(comb[(long long)nidx[j] * 64 + f]);
    xnb[(long long)n * 64 + f] = f2b(acc);
}

// column stats of a bf16 matrix (blockDim.x == ncols)
__global__ void k_colstats_b16(const ushort_t* __restrict__ X, int ncols, int nrows,
                               float* __restrict__ csum, float* __restrict__ csumsq) {
    int c = threadIdx.x;
    int rpb = CDIV(nrows, (int)gridDim.x);
    int r0 = blockIdx.x * rpb;
    int r1 = min(r0 + rpb, nrows);
    float s = 0.f, s2 = 0.f;
    for (int r = r0; r < r1; ++r) {
        float v = b2f(X[(long long)r * ncols + c]);
        s += v; s2 += v * v;
    }
    atomicAdd(&csum[c], s);
    atomicAdd(&csumsq[c], s2);
}

// LDS-tiled transpose+convert: W [K,M] f32 -> Wt [M,K] bf16
__global__ void k_wtrans(const float* __restrict__ W, int K, int M, ushort_t* __restrict__ Wt) {
    __shared__ ushort_t tile[32][33];
    int kb = blockIdx.y * 32, mb = blockIdx.x * 32;
    int tx = threadIdx.x & 31, ty = threadIdx.x >> 5;   // 256 threads: ty 0..7
    for (int dy = ty; dy < 32; dy += 8) {
        int k = kb + dy, m = mb + tx;
        tile[dy][tx] = (k < K && m < M) ? f2b(W[(long long)k * M + m]) : (ushort_t)0;
    }
    __syncthreads();
    for (int dy = ty; dy < 32; dy += 8) {
        int m = mb + dy, k = kb + tx;
        if (m < M && k < K) Wt[(long long)m * K + k] = tile[tx][dy];
    }
}

// LinBlock GEMM, full-M block: C = scale*(act(bn(A)) @ W + bias + res)
// A bf16 staged via LDS (BN+PReLU fused, converted once); Wt bf16 direct from
// global (L2-resident). Output column stats: LDS-reduced per block, then ONE
// global atomicAdd per column per block (was 6144/block -> 183us atomic stall).
template<int KK, int MT, int WR, int WC, int RT>
__global__ __launch_bounds__(512) void k_gemm_fused(
    const ushort_t* __restrict__ A, const ushort_t* __restrict__ Wt,
    const float* __restrict__ bias, const ushort_t* __restrict__ resb,
    const float* __restrict__ csum, const float* __restrict__ csumsq,
    const float* __restrict__ g, const float* __restrict__ bb,
    const float* __restrict__ pr, float scale, int nrows,
    ushort_t* __restrict__ Cb, float* __restrict__ Cf,
    float* __restrict__ osum, float* __restrict__ osumsq) {
    constexpr int RTW = RT / WR;      // rows per wave
    constexpr int MTW = MT / WC;      // cols per wave
    constexpr int FM = RTW / 16;
    constexpr int FN = MTW / 16;
    __shared__ ushort_t sA[RT][36];   // 72B row stride: b64 reads spread banks
    __shared__ float sScl[KK], sOff[KK];
    __shared__ float sStatS[MT], sStatQ[MT];
    int tid = threadIdx.x;
    int wave = tid >> 6, lane = tid & 63;
    int l16 = lane & 15, klo = lane >> 4;
    int wrow = wave / WC, wcol = wave % WC;
    long long rowBase = (long long)blockIdx.x * RT;
    float prs = pr ? pr[0] : 1.0f;
    const float invn = 1.0f / (float)NN;
    for (int c = tid; c < KK; c += 512) {
        float mean = csum[c] * invn;
        float var = csumsq[c] * invn - mean * mean;
        float scl = rsqrtf(var + 1e-5f) * g[c];
        sScl[c] = scl;
        sOff[c] = bb[c] - mean * scl;
    }
    if (osum) {
        for (int c = tid; c < MT; c += 512) { sStatS[c] = 0.f; sStatQ[c] = 0.f; }
    }
    __syncthreads();
    f32x4 acc[FM][FN] = {};
    for (int k0 = 0; k0 < KK; k0 += 32) {
        // stage A: RT rows x 32 k, 8 elems (16B) per thread per iter, BN+act fused
        #pragma unroll
        for (int it = 0; it < RT * 32 / (512 * 8); ++it) {
            int idx = (it * 512 + tid) * 8;
            int r = idx >> 5, kk = idx & 31;
            long long gr = rowBase + r;
            uint4 raw = {0u, 0u, 0u, 0u};
            if (gr < nrows) raw = *(const uint4*)&A[gr * KK + k0 + kk];
            unsigned outw[4];
            #pragma unroll
            for (int q = 0; q < 4; ++q) {
                unsigned rw = ((const unsigned*)&raw)[q];
                int c = k0 + kk + q * 2;
                float t0 = b2f((ushort_t)rw) * sScl[c] + sOff[c];
                float t1 = b2f((ushort_t)(rw >> 16)) * sScl[c + 1] + sOff[c + 1];
                if (t0 < 0.f) t0 *= prs;
                if (t1 < 0.f) t1 *= prs;
                outw[q] = (unsigned)f2b(t0) | ((unsigned)f2b(t1) << 16);
            }
            uint2 w0; w0.x = outw[0]; w0.y = outw[1];
            uint2 w1; w1.x = outw[2]; w1.y = outw[3];
            *(uint2*)&sA[r][kk] = w0;
            *(uint2*)&sA[r][kk + 4] = w1;
        }
        __syncthreads();
        // B frags direct from global Wt[col][k] (L2-resident)
        bf16x8 bfr[FN];
        #pragma unroll
        for (int n = 0; n < FN; ++n) {
            int col = wcol * MTW + n * 16 + l16;
            bfr[n] = *(const bf16x8*)&Wt[(long long)col * KK + k0 + klo * 8];
        }
        // A frags from LDS (2 x b64 each)
        bf16x8 afr[FM];
        #pragma unroll
        for (int m = 0; m < FM; ++m) {
            union { uint2 p[2]; bf16x8 v; } u;
            int row = wrow * RTW + m * 16 + l16;
            u.p[0] = *(const uint2*)&sA[row][klo * 8];
            u.p[1] = *(const uint2*)&sA[row][klo * 8 + 4];
            afr[m] = u.v;
        }
        #pragma unroll
        for (int m = 0; m < FM; ++m)
            #pragma unroll
            for (int n = 0; n < FN; ++n)
                acc[m][n] = __builtin_amdgcn_mfma_f32_16x16x32_bf16(afr[m], bfr[n], acc[m][n], 0, 0, 0);
        __syncthreads();
    }
    // epilogue: C/D col=lane&15, row=(lane>>4)*4+reg; fused bias/res/scale/stats
    #pragma unroll
    for (int m = 0; m < FM; ++m) {
        #pragma unroll
        for (int n = 0; n < FN; ++n) {
            int col = wcol * MTW + n * 16 + l16;
            long long row0 = rowBase + wrow * RTW + m * 16 + klo * 4;
            float bcol = bias[col];
            float s = 0.f, s2 = 0.f;
            #pragma unroll
            for (int r = 0; r < 4; ++r) {
                long long row = row0 + r;
                if (row < nrows) {
                    float v = acc[m][n][r] + bcol;
                    if (resb) v += b2f(resb[row * MT + col]);
                    v *= scale;
                    if (Cf) Cf[row * MT + col] = v;
                    if (Cb) Cb[row * MT + col] = f2b(v);
                    s += v; s2 += v * v;
                }
            }
            if (osum) {
                s += __shfl_down(s, 32, 64);
                s2 += __shfl_down(s2, 32, 64);
                s += __shfl_down(s, 16, 64);
                s2 += __shfl_down(s2, 16, 64);
                if (lane < 16) {
                    atomicAdd(&sStatS[col], s);   // LDS atomic (fast)
                    atomicAdd(&sStatQ[col], s2);
                }
            }
        }
    }
    if (osum) {
        __syncthreads();
        for (int c = tid; c < MT; c += 512) {
            atomicAdd(&osum[c], sStatS[c]);      // 1 global atomic / col / block
            atomicAdd(&osumsq[c], sStatQ[c]);
        }
    }
}

extern "C" void kernel_launch(void* const* d_in, const int* in_sizes, int n_in,
                              void* d_out, int out_size, void* d_ws, size_t ws_size,
                              hipStream_t stream) {
    const float* x       = (const float*)d_in[0];
    const float* eattr   = (const float*)d_in[1];
    const int*   ei      = (const int*)d_in[2];
    const int*   lg      = (const int*)d_in[3];
    const int*   batch   = (const int*)d_in[4];
    const float* W_u     = (const float*)d_in[5];
    const float* W_v     = (const float*)d_in[6];
    const float* W_e     = (const float*)d_in[7];
    const float* gat_W   = (const float*)d_in[8];
    const float* att_s   = (const float*)d_in[9];
    const float* att_d   = (const float*)d_in[10];
    const float* gat_b   = (const float*)d_in[11];
    const float* a_att   = (const float*)d_in[12];
    const float* a_bias  = (const float*)d_in[13];
    const float* W_gout  = (const float*)d_in[14];
    const float* b_gout  = (const float*)d_in[15];
    const float* bn1_g   = (const float*)d_in[16];
    const float* bn1_b   = (const float*)d_in[17];
    const float* lb_W1   = (const float*)d_in[18];
    const float* lb_b1   = (const float*)d_in[19];
    const float* lb_bn_g = (const float*)d_in[20];
    const float* lb_bn_b = (const float*)d_in[21];
    const float* lb_pr   = (const float*)d_in[22];
    const float* lb_W    = (const float*)d_in[23];
    const float* lb_b    = (const float*)d_in[24];
    const float* bn5_g   = (const float*)d_in[25];
    const float* bn5_b   = (const float*)d_in[26];
    const float* pr5     = (const float*)d_in[27];
    const float* lb_W5   = (const float*)d_in[28];
    const float* lb_b5   = (const float*)d_in[29];
    float* out_final = (float*)d_out;

    // ---------------- workspace layout (~186 MB) ----------------
    const long long ESZ = (long long)EE * FF;
    const long long NSZ = (long long)NN * FF;
    char* cur = (char*)d_ws;
    auto alloc = [&](size_t bytes) -> void* {
        void* p = (void*)cur;
        cur += (bytes + 255) & ~(size_t)255;
        return p;
    };
    ushort_t* XU = (ushort_t*)alloc(NSZ * 2);
    ushort_t* XV = (ushort_t*)alloc(NSZ * 2);
    ushort_t* O1 = (ushort_t*)alloc(ESZ * 2);
    ushort_t* O2 = (ushort_t*)alloc(ESZ * 2);
    ushort_t* O3 = (ushort_t*)alloc(ESZ * 2);   // holds EAB until iter-3 overwrites it
    float* XW = (float*)alloc((size_t)EE * 4);
    float* XC = (float*)alloc((size_t)EE * 4);
    ushort_t* XNB = (ushort_t*)alloc(NSZ * 2);
    float* GRAW = (float*)alloc(BBATCH * FF * 4);
    float* G0 = (float*)alloc(BBATCH * FF * 4);
    float* G1 = (float*)alloc(BBATCH * FF * 4);
    float* G2 = (float*)alloc(BBATCH * FF * 4);
    float* SCATT = (float*)alloc(BBATCH * 3 * 4);
    int* BPTR = (int*)alloc((BBATCH + 1) * 4);
    int* LROW = (int*)alloc((size_t)(EE + 1) * 4);
    int* LSRC = (int*)alloc((size_t)LEE * 4);
    int* LCNT = (int*)alloc((size_t)EE * 4);
    int* NROW = (int*)alloc((size_t)(NN + 1) * 4);
    int* NIDX = (int*)alloc((size_t)EE * 4);
    int* NCNT = (int*)alloc((size_t)NN * 4);
    int* SP0 = (int*)alloc(2048 * 4);
    int* SP1 = (int*)alloc(256 * 4);
    float* STATS = (float*)alloc(5 * 2 * SFD * 4);   // 5 stages x (sum, sumsq)[384]
    ushort_t* WT1 = (ushort_t*)alloc((size_t)SFD * FF * 2);       // [384][64]
    ushort_t* WT2 = (ushort_t*)alloc((size_t)SFD * SFD * 2);      // [384][384]
    ushort_t* WT3 = (ushort_t*)alloc((size_t)SFD * SFD * 2);
    ushort_t* WT4 = (ushort_t*)alloc((size_t)SFD * SFD * 2);
    ushort_t* WT5 = (ushort_t*)alloc((size_t)FF * SFD * 2);       // [64][384]
    if ((size_t)(cur - (char*)d_ws) > ws_size) return;  // diagnostic: zeros -> ws too small

    // LinBlock bf16 activations alias the O region (dead by then): 4 x 38.4 MB = 153.6 MB
    ushort_t* T1B = O1;
    ushort_t* T2B = T1B + (long long)NN * SFD;
    ushort_t* T3B = T2B + (long long)NN * SFD;
    ushort_t* T4B = T3B + (long long)NN * SFD;
    float* CS[5][2];
    for (int i = 0; i < 5; ++i) { CS[i][0] = STATS + i * 2 * SFD; CS[i][1] = CS[i][0] + SFD; }
    float* GTS[3] = {G0, G1, G2};

    hipMemsetAsync(STATS, 0, 5 * 2 * SFD * 4, stream);

    // 0. weight transpose+convert (bf16 [col][k]), once per launch
    {
        dim3 gt(SFD / 32, FF / 32);
        k_wtrans<<<gt, 256, 0, stream>>>(lb_W1, FF, SFD, WT1);
        dim3 gs(SFD / 32, SFD / 32);
        k_wtrans<<<gs, 256, 0, stream>>>(lb_W, SFD, SFD, WT2);
        k_wtrans<<<gs, 256, 0, stream>>>(lb_W + (long long)SFD * SFD, SFD, SFD, WT3);
        k_wtrans<<<gs, 256, 0, stream>>>(lb_W + 2LL * SFD * SFD, SFD, SFD, WT4);
        dim3 g5(FF / 32, SFD / 32);
        k_wtrans<<<g5, 256, 0, stream>>>(lb_W5, SFD, FF, WT5);
    }

    // 1. node transforms + batch rowptr
    k_node_mm<<<CDIV(NN, 4), 256, 0, stream>>>(x, W_u, W_v, XU, XV);
    k_batchptr<<<CDIV(EE, 256), 256, 0, stream>>>(batch, BPTR);

    // 2. build line-graph CSR (by dst)
    {
        hipMemsetAsync(LCNT, 0, (size_t)EE * 4, stream);
        k_hist<<<CDIV(LEE, 256), 256, 0, stream>>>(lg + LEE, LEE, LCNT);
        int nb0 = CDIV(EE, 256), nb1 = CDIV(nb0, 256);
        k_part<<<nb0, 256, 0, stream>>>(LCNT, EE, SP0);
        k_part<<<nb1, 256, 0, stream>>>(SP0, nb0, SP1);
        k_scan_single<<<1, 256, 0, stream>>>(SP1, nb1);
        k_scan_add<<<nb1, 256, 0, stream>>>(SP0, nb0, SP1);
        k_scan_out<<<nb0, 256, 0, stream>>>(LCNT, EE, SP0, LROW);
        hipMemsetAsync(LCNT, 0, (size_t)EE * 4, stream);
        k_fill_lg<<<CDIV(LEE, 256), 256, 0, stream>>>(lg, LROW, LCNT, LSRC);
    }
    // 3. build node CSR (by ei1)
    {
        hipMemsetAsync(NCNT, 0, (size_t)NN * 4, stream);
        k_hist<<<CDIV(EE, 256), 256, 0, stream>>>(ei + EE, EE, NCNT);
        int nb0 = CDIV(NN, 256), nb1 = CDIV(nb0, 256);
        k_part<<<nb0, 256, 0, stream>>>(NCNT, NN, SP0);
        k_part<<<nb1, 256, 0, stream>>>(SP0, nb0, SP1);
        k_scan_single<<<1, 256, 0, stream>>>(SP1, nb1);
        k_scan_add<<<nb1, 256, 0, stream>>>(SP0, nb0, SP1);
        k_scan_out<<<nb0, 256, 0, stream>>>(NCNT, NN, SP0, NROW);
        hipMemsetAsync(NCNT, 0, (size_t)NN * 4, stream);
        k_fill_n<<<CDIV(EE, 256), 256, 0, stream>>>(ei, NROW, NCNT, NIDX);
    }

    const int EB8 = CDIV(EE, 8);

    auto gat_pool = [&](ushort_t* buf, int t) {
        k_gat_fused<<<CDIV(EE, 256), 256, 0, stream>>>(XW, LROW, LSRC, att_s, att_d, gat_b, XC);
        k_pool<<<BBATCH, 256, 0, stream>>>(XC, buf, BPTR, GRAW);
        k_gout_mm<<<CDIV(BBATCH, 4), 256, 0, stream>>>(GRAW, W_gout, b_gout, GTS[t]);
    };

    // 4. EAB + message-passing iterations (uniform gathers, bf16 storage)
    k_ea_b16<<<EB8, 256, 0, stream>>>(XU, XV, eattr, W_e, ei, O3);              // O3 = EAB
    k_mp_gather<<<EB8, 256, 0, stream>>>(O3, O3, LROW, LSRC, gat_W, O1, XW);    // O1 = out1
    gat_pool(O1, 0);
    k_mp_gather<<<EB8, 256, 0, stream>>>(O1, O3, LROW, LSRC, gat_W, O2, XW);    // O2 = out2
    gat_pool(O2, 1);
    k_mp_gather<<<EB8, 256, 0, stream>>>(O2, O3, LROW, LSRC, gat_W, O3, XW);    // O3 = out3
    gat_pool(O3, 2);

    // 5. iteration attention + combine + node aggregation (writes bf16 XNB)
    k_att<<<BBATCH, 64, 0, stream>>>(G0, G1, G2, a_att, a_bias, SCATT);
    k_comb<<<(int)CDIV(ESZ, 256), 256, 0, stream>>>(O1, O2, O3, SCATT, batch);
    k_node_gather<<<CDIV(NN, 4), 256, 0, stream>>>(O1, NROW, NIDX, x, XNB);
    k_colstats_b16<<<256, FF, 0, stream>>>(XNB, FF, NN, CS[0][0], CS[0][1]);

    // 6. LinBlock: full-M MFMA GEMMs, BN fused, stats fused into epilogues
    {
        const int GB128 = CDIV(NN, 128);   // 391
        // lin1: x1 = bn1(xn) @ W1 + b1    (K=64, no prelu)
        k_gemm_fused<64, 384, 2, 4, 128><<<GB128, 512, 0, stream>>>(XNB, WT1, lb_b1, nullptr,
            CS[0][0], CS[0][1], bn1_g, bn1_b, nullptr, 1.0f, NN,
            T1B, nullptr, CS[1][0], CS[1][1]);
        // lin2: h1 = prelu(bn(x1)) @ W[0] + b[0]
        k_gemm_fused<384, 384, 2, 4, 128><<<GB128, 512, 0, stream>>>(T1B, WT2, lb_b, nullptr,
            CS[1][0], CS[1][1], lb_bn_g, lb_bn_b, lb_pr, 1.0f, NN,
            T2B, nullptr, CS[2][0], CS[2][1]);
        // lin3: x2 = (prelu(bn(h1)) @ W[1] + b[1] + x1) / 2
        k_gemm_fused<384, 384, 2, 4, 128><<<GB128, 512, 0, stream>>>(T2B, WT3, lb_b + SFD, T1B,
            CS[2][0], CS[2][1], lb_bn_g + SFD, lb_bn_b + SFD, lb_pr + 1, 0.5f, NN,
            T3B, nullptr, CS[3][0], CS[3][1]);
        // lin4: x3 = (prelu(bn(x2)) @ W[2] + b[2] + x2) / 2
        k_gemm_fused<384, 384, 2, 4, 128><<<GB128, 512, 0, stream>>>(T3B, WT4, lb_b + 2 * SFD, T3B,
            CS[3][0], CS[3][1], lb_bn_g + 2 * SFD, lb_bn_b + 2 * SFD, lb_pr + 2, 0.5f, NN,
            T4B, nullptr, CS[4][0], CS[4][1]);
        // lin5: out = prelu(bn5(x3)) @ W5 + b5    (f32 out, 256x64 tile)
        k_gemm_fused<384, 64, 8, 1, 256><<<CDIV(NN, 256), 512, 0, stream>>>(T4B, WT5, lb_b5, nullptr,
            CS[4][0], CS[4][1], bn5_g, bn5_b, pr5, 1.0f, NN,
            nullptr, out_final, nullptr, nullptr);
    }
}